// Round 6
// baseline (1826.026 us; speedup 1.0000x reference)
//
#include <hip/hip_runtime.h>
#include <hip/hip_bf16.h>
#include <cstdint>
#include <cstddef>

#define DEV __device__ __forceinline__

using f32x4 = __attribute__((ext_vector_type(4))) float;
using bfx8  = __attribute__((ext_vector_type(8))) __bf16;
using s16x8 = __attribute__((ext_vector_type(8))) short;

// ---------- helpers ----------
DEV uint16_t f2bf(float f) {
    union { float f; uint32_t u; } x; x.f = f;
    uint32_t r = x.u + 0x7fffu + ((x.u >> 16) & 1u);   // RNE
    return (uint16_t)(r >> 16);
}

DEV float gelu_exact(float v) {
    return 0.5f * v * (1.0f + erff(v * 0.70710678118654752f));
}

DEV f32x4 mfma16(s16x8 a, s16x8 b, f32x4 c) {
    return __builtin_amdgcn_mfma_f32_16x16x32_bf16(
        __builtin_bit_cast(bfx8, a), __builtin_bit_cast(bfx8, b), c, 0, 0, 0);
}

DEV void async_lds16(const void* g, void* l) {
    __builtin_amdgcn_global_load_lds(
        (const __attribute__((address_space(1))) uint32_t*)g,
        (__attribute__((address_space(3))) uint32_t*)l, 16, 0, 0);
}

template<int N> DEV void wait_vmcnt() {
    if constexpr (N == 0)      asm volatile("s_waitcnt vmcnt(0)" ::: "memory");
    else if constexpr (N == 4) asm volatile("s_waitcnt vmcnt(4)" ::: "memory");
    else static_assert(N == 0 || N == 4, "add vmcnt literal");
}
#define SBAR      asm volatile("s_barrier" ::: "memory")
#define LGKM0     asm volatile("s_waitcnt lgkmcnt(0)" ::: "memory")
#define SCHED0    __builtin_amdgcn_sched_barrier(0)

// ---------- LayerNorm: f32 [rows,512] -> bf16, one wave per row ----------
DEV void ln_row(const float* __restrict__ in, const float* __restrict__ sc,
                const float* __restrict__ bi, uint16_t* __restrict__ out, size_t row)
{
    const int lane = threadIdx.x & 63;
    const float* p = in + row * 512 + lane * 8;
    float4 a = *(const float4*)p;
    float4 b4 = *(const float4*)(p + 4);
    float v[8] = {a.x, a.y, a.z, a.w, b4.x, b4.y, b4.z, b4.w};
    float s = 0.f, sq = 0.f;
#pragma unroll
    for (int j = 0; j < 8; ++j) { s += v[j]; sq += v[j] * v[j]; }
#pragma unroll
    for (int o = 1; o < 64; o <<= 1) { s += __shfl_xor(s, o); sq += __shfl_xor(sq, o); }
    const float mean = s * (1.0f / 512.0f);
    const float var  = sq * (1.0f / 512.0f) - mean * mean;
    const float rstd = rsqrtf(var + 1e-5f);
    const int c = lane * 8;
    uint16_t o8[8];
#pragma unroll
    for (int j = 0; j < 8; ++j)
        o8[j] = f2bf((v[j] - mean) * rstd * sc[c + j] + bi[c + j]);
    uint4 pk;
    pk.x = (uint32_t)o8[0] | ((uint32_t)o8[1] << 16);
    pk.y = (uint32_t)o8[2] | ((uint32_t)o8[3] << 16);
    pk.z = (uint32_t)o8[4] | ((uint32_t)o8[5] << 16);
    pk.w = (uint32_t)o8[6] | ((uint32_t)o8[7] << 16);
    *reinterpret_cast<uint4*>(out + row * 512 + c) = pk;
}

__global__ __launch_bounds__(256)
void ln_bf16(const float* __restrict__ in, const float* __restrict__ sc,
             const float* __restrict__ bi, uint16_t* __restrict__ out)
{
    ln_row(in, sc, bi, out, (size_t)blockIdx.x * 4 + (threadIdx.x >> 6));
}

__global__ __launch_bounds__(256)
void ln2_bf16(const float* __restrict__ in0, const float* __restrict__ sc0,
              const float* __restrict__ bi0, uint16_t* __restrict__ out0,
              const float* __restrict__ in1, const float* __restrict__ sc1,
              const float* __restrict__ bi1, uint16_t* __restrict__ out1)
{
    const int sel = blockIdx.x >> 10;
    const size_t row = (size_t)(blockIdx.x & 1023) * 4 + (threadIdx.x >> 6);
    if (sel == 0) ln_row(in0, sc0, bi0, out0, row);
    else          ln_row(in1, sc1, bi1, out1, row);
}

// ---------- weight transpose-convert: f32 [L][K][N] -> bf16 [L][row0+N][K] ----------
__global__ __launch_bounds__(256)
void wtrans(const float* __restrict__ W, uint16_t* __restrict__ WT, int K, int N,
            size_t lstride, int row0)
{
    __shared__ float tile[32][33];
    const int l = blockIdx.z;
    const int k0 = blockIdx.x * 32, n0 = blockIdx.y * 32;
    const float* Wl = W + (size_t)l * K * N;
    uint16_t* WTl = WT + (size_t)l * lstride;
    const int tx = threadIdx.x, ty = threadIdx.y;  // (32,8)
#pragma unroll
    for (int j = 0; j < 4; ++j)
        tile[ty + j * 8][tx] = Wl[(size_t)(k0 + ty + j * 8) * N + n0 + tx];
    __syncthreads();
#pragma unroll
    for (int j = 0; j < 4; ++j)
        WTl[(size_t)(row0 + n0 + ty + j * 8) * K + k0 + tx] = f2bf(tile[tx][ty + j * 8]);
}

// ---------- per-head V transpose: bf16 src [4096][C] (head at coff+h*64) -> vt [32][64][1024] ----------
__global__ __launch_bounds__(256)
void vtrans(const uint16_t* __restrict__ src, uint16_t* __restrict__ vt, int C, int coff)
{
    __shared__ uint16_t tile[64][72];
    const int n0 = blockIdx.x * 64;
    const int bh = blockIdx.y, b = bh >> 3, h = bh & 7;
    const int tx = threadIdx.x, ty = threadIdx.y;  // (64,4)
#pragma unroll
    for (int j = 0; j < 16; ++j) {
        const int n = ty + j * 4;
        tile[n][tx] = src[((size_t)b * 1024 + n0 + n) * C + coff + h * 64 + tx];
    }
    __syncthreads();
    uint16_t* o = vt + (size_t)bh * 65536;
#pragma unroll
    for (int j = 0; j < 16; ++j) {
        const int d = ty + j * 4;
        o[(size_t)d * 1024 + n0 + tx] = tile[tx][d];
    }
}

// ---------- GEMM v5: counted-vmcnt depth-2, XCD swizzle, optional split-K ----------
// C[M,N] = A[M,K] @ BT[N,K]^T. PARTIAL: blockIdx.y selects K-chunk [y*kh, (y+1)*kh),
// writes f32 partials to outp + y*M*N.
template<int BM, int BN, int NWR, int NWC, int MINW,
         int HAS_BIAS, int HAS_RESID, int DO_GELU, int OUT_BF16, int PARTIAL>
__global__ __launch_bounds__(NWR * NWC * 64, MINW)
void gemm5(const uint16_t* __restrict__ A, const uint16_t* __restrict__ BT,
           const float* __restrict__ bias, const float* __restrict__ resid,
           void* __restrict__ outp, int M, int N, int K, int kh)
{
    constexpr int NT = NWR * NWC * 64;
    constexpr int WM = BM / NWR, WN = BN / NWC;
    constexpr int FM = WM / 16, FN = WN / 16;
    constexpr int ASLOTS = 8 * BM, BSLOTS = 8 * BN, TOT = ASLOTS + BSLOTS;
    constexpr int S = TOT / NT;   // per-thread loads per stage (vmcnt unit)
    static_assert(S == 4, "vmcnt literal assumes S==4");
    __shared__ uint16_t As[2][ASLOTS * 8];
    __shared__ uint16_t Bs[2][BSLOTS * 8];
    const int tid = threadIdx.x, lane = tid & 63;
    const int w = tid >> 6, wr = w / NWC, wc = w % NWC;
    const int kg = lane >> 4, lr = lane & 15;
    // bijective XCD swizzle (all grid.x % 8 == 0)
    const int nwg = gridDim.x;
    const int id0 = blockIdx.x;
    const int id = (id0 & 7) * (nwg >> 3) + (id0 >> 3);
    const int nbn = N / BN;
    const size_t m0 = (size_t)(id / nbn) * BM;
    const size_t n0 = (size_t)(id % nbn) * BN;
    const int kbase = PARTIAL ? blockIdx.y * kh : 0;

    auto stage = [&](int b, int k0) {
#pragma unroll
        for (int j = 0; j < S; ++j) {
            const int s = j * NT + tid;
            if (s < ASLOTS) {
                const int sub = s / BM, row = s % BM;
                async_lds16(A + (m0 + row) * K + k0 + sub * 8, &As[b][s * 8]);
            } else {
                const int s2 = s - ASLOTS;
                const int sub = s2 / BN, row = s2 % BN;
                async_lds16(BT + (n0 + row) * K + k0 + sub * 8, &Bs[b][s2 * 8]);
            }
        }
    };

    f32x4 acc[FM][FN] = {};
    const int nt = kh / 64;
    stage(0, kbase);
    stage(1, kbase + 64);
    int cur = 0;
    for (int t = 0; t < nt; ++t) {
        if (t < nt - 1) wait_vmcnt<S>(); else wait_vmcnt<0>();
        SBAR;                       // all waves' tile-t loads landed
        s16x8 af[2][FM], bf[2][FN];
#pragma unroll
        for (int ks = 0; ks < 2; ++ks) {
#pragma unroll
            for (int i = 0; i < FM; ++i)
                af[ks][i] = *(const s16x8*)&As[cur][((ks * 4 + kg) * BM + wr * WM + i * 16 + lr) * 8];
#pragma unroll
            for (int j = 0; j < FN; ++j)
                bf[ks][j] = *(const s16x8*)&Bs[cur][((ks * 4 + kg) * BN + wc * WN + j * 16 + lr) * 8];
        }
        __builtin_amdgcn_s_setprio(1);
#pragma unroll
        for (int ks = 0; ks < 2; ++ks)
#pragma unroll
            for (int i = 0; i < FM; ++i)
#pragma unroll
                for (int j = 0; j < FN; ++j)
                    acc[i][j] = mfma16(af[ks][i], bf[ks][j], acc[i][j]);
        __builtin_amdgcn_s_setprio(0);
        LGKM0; SCHED0;              // all my ds_reads landed (rule #18 fence)
        SBAR;                       // all waves done reading buf[cur]
        if (t + 2 < nt) stage(cur, kbase + (t + 2) * 64);
        cur ^= 1;
    }
    float* pout = PARTIAL ? (float*)outp + (size_t)blockIdx.y * M * (size_t)N : nullptr;
#pragma unroll
    for (int i = 0; i < FM; ++i) {
        const size_t rbase = m0 + wr * WM + i * 16 + kg * 4;
#pragma unroll
        for (int j = 0; j < FN; ++j) {
            const size_t col = n0 + wc * WN + j * 16 + lr;
            const float bval = HAS_BIAS ? bias[col] : 0.0f;
#pragma unroll
            for (int r = 0; r < 4; ++r) {
                const size_t row = rbase + r;
                float v = acc[i][j][r] + bval;
                if (PARTIAL) { pout[row * (size_t)N + col] = v; continue; }
                if (DO_GELU)  v = gelu_exact(v);
                if (HAS_RESID) v += resid[row * (size_t)N + col];
                if (OUT_BF16) ((uint16_t*)outp)[row * (size_t)N + col] = f2bf(v);
                else          ((float*)outp)[row * (size_t)N + col] = v;
            }
        }
    }
}

// ---------- split-K reduce: x = p0 + p1 + bias + x  (f32, [4096][512]) ----------
__global__ __launch_bounds__(256)
void reduce2(const float* __restrict__ p, const float* __restrict__ bias,
             float* __restrict__ x)
{
    const size_t i = ((size_t)blockIdx.x * 256 + threadIdx.x) * 8;
    const int col = (int)(i & 511);
    const float* q = p + 4096ull * 512;
    float4 a0 = *(const float4*)(p + i),     a1 = *(const float4*)(p + i + 4);
    float4 b0 = *(const float4*)(q + i),     b1 = *(const float4*)(q + i + 4);
    float4 s0 = *(const float4*)(bias + col), s1 = *(const float4*)(bias + col + 4);
    float4 r0 = *(const float4*)(x + i),     r1 = *(const float4*)(x + i + 4);
    float4 o0, o1;
    o0.x = a0.x + b0.x + s0.x + r0.x;  o0.y = a0.y + b0.y + s0.y + r0.y;
    o0.z = a0.z + b0.z + s0.z + r0.z;  o0.w = a0.w + b0.w + s0.w + r0.w;
    o1.x = a1.x + b1.x + s1.x + r1.x;  o1.y = a1.y + b1.y + s1.y + r1.y;
    o1.z = a1.z + b1.z + s1.z + r1.z;  o1.w = a1.w + b1.w + s1.w + r1.w;
    *(float4*)(x + i) = o0;
    *(float4*)(x + i + 4) = o1;
}

// ---------- flash attention: no-max softmax, fragment-ordered LDS, 1 barrier/tile ----------
__global__ __launch_bounds__(256)
void attn_flash(const uint16_t* __restrict__ Qb, const uint16_t* __restrict__ Kb,
                const uint16_t* __restrict__ Vt, uint16_t* __restrict__ Ob,
                int qstride, int kstride, int qoff, int koff)
{
    __shared__ uint16_t Ks[2][4096];   // [sub=d/8 8][kv 64][8] fragment-ordered
    __shared__ uint16_t Vs[2][4096];   // [sub=kv/8 8][d 64][8] fragment-ordered
    __shared__ uint16_t Pb[4][1024];   // per-wave [sub=kv/8 8][qrow 16][8] fragment-ordered
    const int tid = threadIdx.x, lane = tid & 63, w = tid >> 6;
    const int kg = lane >> 4, lr = lane & 15;
    const int bh = blockIdx.y, b = bh >> 3, h = bh & 7;
    const int q0 = blockIdx.x * 64;
    const float CEXP = 0.125f * 1.44269504f;   // scale * log2(e)

    s16x8 aq0, aq1;
    {
        const size_t qrow = (size_t)b * 1024 + q0 + w * 16 + lr;
        const uint16_t* qp = Qb + qrow * qstride + qoff + h * 64 + kg * 8;
        aq0 = *(const s16x8*)qp;
        aq1 = *(const s16x8*)(qp + 32);
    }
    const uint16_t* kbase = Kb + (size_t)b * 1024 * kstride + koff + h * 64;
    const uint16_t* vbase = Vt + (size_t)bh * 65536;

    float l_r[4] = {0.f, 0.f, 0.f, 0.f};
    f32x4 acc[4] = {};

    auto stage = [&](int buf, int kv0) {
#pragma unroll
        for (int j = 0; j < 2; ++j) {
            const int s = j * 256 + tid;          // 0..511
            const int sub = s >> 6, row = s & 63;
            async_lds16(kbase + (size_t)(kv0 + row) * kstride + sub * 8, &Ks[buf][s * 8]);
            async_lds16(vbase + (size_t)row * 1024 + kv0 + sub * 8,      &Vs[buf][s * 8]);
        }
    };

    stage(0, 0);
    __syncthreads();
    int cur = 0;
    for (int t = 0; t < 16; ++t) {
        if (t < 15) stage(cur ^ 1, (t + 1) * 64);
        // S = Q K^T
        f32x4 s4[4];
        __builtin_amdgcn_s_setprio(1);
#pragma unroll
        for (int ni = 0; ni < 4; ++ni) {
            s16x8 bk0 = *(const s16x8*)&Ks[cur][(kg * 64 + ni * 16 + lr) * 8];
            s16x8 bk1 = *(const s16x8*)&Ks[cur][((4 + kg) * 64 + ni * 16 + lr) * 8];
            f32x4 z = {};
            z = mfma16(aq0, bk0, z);
            z = mfma16(aq1, bk1, z);
            s4[ni] = z;
        }
        __builtin_amdgcn_s_setprio(0);
#pragma unroll
        for (int ni = 0; ni < 4; ++ni) {
            const int slotb = (ni * 2 + (lr >> 3)) * 16 + kg * 4;
#pragma unroll
            for (int r = 0; r < 4; ++r) {
                const float pe = __builtin_amdgcn_exp2f(s4[ni][r] * CEXP);
                l_r[r] += pe;
                Pb[w][(slotb + r) * 8 + (lr & 7)] = f2bf(pe);
            }
        }
        s16x8 ap0 = *(const s16x8*)&Pb[w][(kg * 16 + lr) * 8];
        s16x8 ap1 = *(const s16x8*)&Pb[w][((4 + kg) * 16 + lr) * 8];
        // O += P @ V
        __builtin_amdgcn_s_setprio(1);
#pragma unroll
        for (int ni = 0; ni < 4; ++ni) {
            s16x8 bv0 = *(const s16x8*)&Vs[cur][(kg * 64 + ni * 16 + lr) * 8];
            s16x8 bv1 = *(const s16x8*)&Vs[cur][((4 + kg) * 64 + ni * 16 + lr) * 8];
            acc[ni] = mfma16(ap0, bv0, acc[ni]);
            acc[ni] = mfma16(ap1, bv1, acc[ni]);
        }
        __builtin_amdgcn_s_setprio(0);
        __syncthreads();
        cur ^= 1;
    }
    float linv[4];
#pragma unroll
    for (int r = 0; r < 4; ++r) {
        float l = l_r[r];
        l += __shfl_xor(l, 1); l += __shfl_xor(l, 2);
        l += __shfl_xor(l, 4); l += __shfl_xor(l, 8);
        linv[r] = 1.0f / l;
    }
#pragma unroll
    for (int ni = 0; ni < 4; ++ni)
#pragma unroll
        for (int r = 0; r < 4; ++r) {
            const float v = acc[ni][r] * linv[r];
            const size_t row = (size_t)b * 1024 + q0 + w * 16 + kg * 4 + r;
            Ob[row * 512 + h * 64 + ni * 16 + lr] = f2bf(v);
        }
}

// ---------- host ----------
extern "C" void kernel_launch(void* const* d_in, const int* in_sizes, int n_in,
                              void* d_out, int out_size, void* d_ws, size_t ws_size,
                              hipStream_t stream)
{
    (void)in_sizes; (void)n_in; (void)out_size; (void)ws_size;
    const float* g     = (const float*)d_in[0];
    const float* x0    = (const float*)d_in[1];
    const float* ln1_s = (const float*)d_in[2];
    const float* ln1_b = (const float*)d_in[3];
    const float* Wqkv  = (const float*)d_in[4];
    const float* Wo_sa = (const float*)d_in[5];
    const float* bo_sa = (const float*)d_in[6];
    const float* lng_s = (const float*)d_in[7];
    const float* lng_b = (const float*)d_in[8];
    const float* lnx_s = (const float*)d_in[9];
    const float* lnx_b = (const float*)d_in[10];
    const float* Wq    = (const float*)d_in[11];
    const float* Wk    = (const float*)d_in[12];
    const float* Wv    = (const float*)d_in[13];
    const float* bv    = (const float*)d_in[14];
    const float* Wo_ca = (const float*)d_in[15];
    const float* bo_ca = (const float*)d_in[16];
    const float* lnf_s = (const float*)d_in[17];
    const float* lnf_b = (const float*)d_in[18];
    const float* W1    = (const float*)d_in[19];
    const float* b1    = (const float*)d_in[20];
    const float* W2    = (const float*)d_in[21];
    const float* b2    = (const float*)d_in[22];

    float* x = (float*)d_out;  // running residual stream (f32)

    char* p = (char*)d_ws;
    auto carve = [&](size_t n) { char* r = p; p += (n + 255) & ~(size_t)255; return r; };
    uint16_t* WqkT  = (uint16_t*)carve(6ull * 1024 * 512 * 2);  // [l][Wq^T(512) | Wk^T(512)][512]
    uint16_t* WvT   = (uint16_t*)carve(6ull * 512 * 512 * 2);
    uint16_t* WocaT = (uint16_t*)carve(6ull * 512 * 512 * 2);
    uint16_t* WqkvT = (uint16_t*)carve(6ull * 1536 * 512 * 2);
    uint16_t* WosaT = (uint16_t*)carve(6ull * 512 * 512 * 2);
    uint16_t* W1T   = (uint16_t*)carve(6ull * 2048 * 512 * 2);
    uint16_t* W2T   = (uint16_t*)carve(6ull * 512 * 2048 * 2);
    uint16_t* gn    = (uint16_t*)carve(4096ull * 512 * 2);
    uint16_t* xn    = (uint16_t*)carve(4096ull * 512 * 2);
    uint16_t* qkvu  = (uint16_t*)carve(4096ull * 1536 * 2);  // union: {qk[4096][1024], vb[4096][512]} | qkv
    uint16_t* vt    = (uint16_t*)carve(32ull * 64 * 1024 * 2);
    uint16_t* ab    = (uint16_t*)carve(4096ull * 512 * 2);
    uint16_t* hb    = (uint16_t*)carve(4096ull * 2048 * 2);
    float*    pk2   = (float*)carve(2ull * 4096 * 512 * 4);   // split-K partials
    uint16_t* qk = qkvu;
    uint16_t* vb = qkvu + 4096ull * 1024;

    // weight prep: transpose-convert all weights to bf16 [N][K]
    dim3 tb(32, 8);
    wtrans<<<dim3(16, 16, 6), tb, 0, stream>>>(Wq,    WqkT,  512, 512,  1024ull * 512, 0);
    wtrans<<<dim3(16, 16, 6), tb, 0, stream>>>(Wk,    WqkT,  512, 512,  1024ull * 512, 512);
    wtrans<<<dim3(16, 16, 6), tb, 0, stream>>>(Wv,    WvT,   512, 512,  512ull * 512, 0);
    wtrans<<<dim3(16, 16, 6), tb, 0, stream>>>(Wo_ca, WocaT, 512, 512,  512ull * 512, 0);
    wtrans<<<dim3(16, 48, 6), tb, 0, stream>>>(Wqkv,  WqkvT, 512, 1536, 1536ull * 512, 0);
    wtrans<<<dim3(16, 16, 6), tb, 0, stream>>>(Wo_sa, WosaT, 512, 512,  512ull * 512, 0);
    wtrans<<<dim3(16, 64, 6), tb, 0, stream>>>(W1,    W1T,   512, 2048, 2048ull * 512, 0);
    wtrans<<<dim3(64, 16, 6), tb, 0, stream>>>(W2,    W2T,   2048, 512, 2048ull * 512, 0);

    hipMemcpyAsync(x, x0, 4096ull * 512 * 4, hipMemcpyDeviceToDevice, stream);

    const dim3 ga(16, 32), va(16, 32), vb4(64, 4);

    for (int l = 0; l < 6; ++l) {
        const size_t o512 = (size_t)l * 512, oW = (size_t)l * 512 * 512;
        const size_t oW1 = (size_t)l * 2048 * 512, oWqkv = (size_t)l * 1536 * 512;
        const size_t o2048 = (size_t)l * 2048;

        // ---- relational cross attention ----
        ln2_bf16<<<2048, 256, 0, stream>>>(g, lng_s + o512, lng_b + o512, gn,
                                           x, lnx_s + o512, lnx_b + o512, xn);
        gemm5<128, 128, 2, 4, 4, 0, 0, 0, 1, 0><<<256, 512, 0, stream>>>(
            gn, WqkT + (size_t)l * 1024 * 512, nullptr, nullptr, qk, 4096, 1024, 512, 512);
        gemm5<64, 64, 2, 2, 4, 1, 0, 0, 1, 0><<<512, 256, 0, stream>>>(
            xn, WvT + oW, bv + o512, nullptr, vb, 4096, 512, 512, 512);
        vtrans<<<va, vb4, 0, stream>>>(vb, vt, 512, 0);
        attn_flash<<<ga, 256, 0, stream>>>(qk, qk, vt, ab, 1024, 1024, 0, 512);
        gemm5<64, 64, 2, 2, 4, 1, 1, 0, 0, 0><<<512, 256, 0, stream>>>(
            ab, WocaT + oW, bo_ca + o512, x, x, 4096, 512, 512, 512);

        // ---- feed-forward ----
        ln_bf16<<<1024, 256, 0, stream>>>(x, lnf_s + o512, lnf_b + o512, xn);
        gemm5<64, 64, 2, 2, 4, 1, 0, 1, 1, 0><<<2048, 256, 0, stream>>>(
            xn, W1T + oW1, b1 + o2048, nullptr, hb, 4096, 2048, 512, 512);
        gemm5<64, 64, 2, 2, 4, 0, 0, 0, 0, 1><<<dim3(512, 2), 256, 0, stream>>>(
            hb, W2T + oW1, nullptr, nullptr, pk2, 4096, 512, 2048, 1024);
        reduce2<<<1024, 256, 0, stream>>>(pk2, b2 + o512, x);

        // ---- pre-norm self attention ----
        ln_bf16<<<1024, 256, 0, stream>>>(x, ln1_s + o512, ln1_b + o512, xn);
        gemm5<128, 128, 2, 4, 4, 0, 0, 0, 1, 0><<<384, 512, 0, stream>>>(
            xn, WqkvT + oWqkv, nullptr, nullptr, qkvu, 4096, 1536, 512, 512);
        vtrans<<<va, vb4, 0, stream>>>(qkvu, vt, 1536, 1024);
        attn_flash<<<ga, 256, 0, stream>>>(qkvu, qkvu, vt, ab, 1536, 1536, 0, 512);
        gemm5<64, 64, 2, 2, 4, 1, 1, 0, 0, 0><<<512, 256, 0, stream>>>(
            ab, WosaT + oW, bo_sa + o512, x, x, 4096, 512, 512, 512);

        // ---- feed-forward ----
        ln_bf16<<<1024, 256, 0, stream>>>(x, lnf_s + o512, lnf_b + o512, xn);
        gemm5<64, 64, 2, 2, 4, 1, 0, 1, 1, 0><<<2048, 256, 0, stream>>>(
            xn, W1T + oW1, b1 + o2048, nullptr, hb, 4096, 2048, 512, 512);
        gemm5<64, 64, 2, 2, 4, 0, 0, 0, 0, 1><<<dim3(512, 2), 256, 0, stream>>>(
            hb, W2T + oW1, nullptr, nullptr, pk2, 4096, 512, 2048, 1024);
        reduce2<<<1024, 256, 0, stream>>>(pk2, b2 + o512, x);
    }
}

// Round 7
// 1649.066 us; speedup vs baseline: 1.1073x; 1.1073x over previous
//
#include <hip/hip_runtime.h>
#include <hip/hip_bf16.h>
#include <cstdint>
#include <cstddef>

#define DEV __device__ __forceinline__

using f32x4 = __attribute__((ext_vector_type(4))) float;
using bfx8  = __attribute__((ext_vector_type(8))) __bf16;
using s16x8 = __attribute__((ext_vector_type(8))) short;

// ---------- helpers ----------
DEV uint16_t f2bf(float f) {
    union { float f; uint32_t u; } x; x.f = f;
    uint32_t r = x.u + 0x7fffu + ((x.u >> 16) & 1u);   // RNE
    return (uint16_t)(r >> 16);
}

DEV float gelu_exact(float v) {
    return 0.5f * v * (1.0f + erff(v * 0.70710678118654752f));
}

DEV f32x4 mfma16(s16x8 a, s16x8 b, f32x4 c) {
    return __builtin_amdgcn_mfma_f32_16x16x32_bf16(
        __builtin_bit_cast(bfx8, a), __builtin_bit_cast(bfx8, b), c, 0, 0, 0);
}

DEV void async_lds16(const void* g, void* l) {
    __builtin_amdgcn_global_load_lds(
        (const __attribute__((address_space(1))) uint32_t*)g,
        (__attribute__((address_space(3))) uint32_t*)l, 16, 0, 0);
}

template<int N> DEV void wait_vmcnt() {
    if constexpr (N == 0)      asm volatile("s_waitcnt vmcnt(0)" ::: "memory");
    else if constexpr (N == 4) asm volatile("s_waitcnt vmcnt(4)" ::: "memory");
    else static_assert(N == 0 || N == 4, "add vmcnt literal");
}
#define SBAR      asm volatile("s_barrier" ::: "memory")
#define LGKM0     asm volatile("s_waitcnt lgkmcnt(0)" ::: "memory")
#define SCHED0    __builtin_amdgcn_sched_barrier(0)

// ---------- LayerNorm: f32 [rows,512] -> bf16 (optional scale/bias), one wave/row ----------
template<int HAS_SB>
__global__ __launch_bounds__(256)
void ln_t(const float* __restrict__ in, const float* __restrict__ sc,
          const float* __restrict__ bi, uint16_t* __restrict__ out)
{
    const int lane = threadIdx.x & 63;
    const size_t row = (size_t)blockIdx.x * 4 + (threadIdx.x >> 6);
    const float* p = in + row * 512 + lane * 8;
    float4 a = *(const float4*)p;
    float4 b4 = *(const float4*)(p + 4);
    float v[8] = {a.x, a.y, a.z, a.w, b4.x, b4.y, b4.z, b4.w};
    float s = 0.f, sq = 0.f;
#pragma unroll
    for (int j = 0; j < 8; ++j) { s += v[j]; sq += v[j] * v[j]; }
#pragma unroll
    for (int o = 1; o < 64; o <<= 1) { s += __shfl_xor(s, o); sq += __shfl_xor(sq, o); }
    const float mean = s * (1.0f / 512.0f);
    const float var  = sq * (1.0f / 512.0f) - mean * mean;
    const float rstd = rsqrtf(var + 1e-5f);
    const int c = lane * 8;
    uint16_t o8[8];
#pragma unroll
    for (int j = 0; j < 8; ++j) {
        float z = (v[j] - mean) * rstd;
        if (HAS_SB) z = z * sc[c + j] + bi[c + j];
        o8[j] = f2bf(z);
    }
    uint4 pk;
    pk.x = (uint32_t)o8[0] | ((uint32_t)o8[1] << 16);
    pk.y = (uint32_t)o8[2] | ((uint32_t)o8[3] << 16);
    pk.z = (uint32_t)o8[4] | ((uint32_t)o8[5] << 16);
    pk.w = (uint32_t)o8[6] | ((uint32_t)o8[7] << 16);
    *reinterpret_cast<uint4*>(out + row * 512 + c) = pk;
}

// ---------- weight transpose-convert: f32 [L][K][N] -> bf16 [L][row0+N][K], opt row-scale ----------
__global__ __launch_bounds__(256)
void wtrans(const float* __restrict__ W, uint16_t* __restrict__ WT, int K, int N,
            size_t lstride, int row0, const float* __restrict__ kscale)
{
    __shared__ float tile[32][33];
    const int l = blockIdx.z;
    const int k0 = blockIdx.x * 32, n0 = blockIdx.y * 32;
    const float* Wl = W + (size_t)l * K * N;
    uint16_t* WTl = WT + (size_t)l * lstride;
    const int tx = threadIdx.x, ty = threadIdx.y;  // (32,8)
#pragma unroll
    for (int j = 0; j < 4; ++j) {
        const int k = k0 + ty + j * 8;
        float w = Wl[(size_t)k * N + n0 + tx];
        if (kscale) w *= kscale[l * K + k];
        tile[ty + j * 8][tx] = w;
    }
    __syncthreads();
#pragma unroll
    for (int j = 0; j < 4; ++j)
        WTl[(size_t)(row0 + n0 + ty + j * 8) * K + k0 + tx] = f2bf(tile[tx][ty + j * 8]);
}

// ---------- bias fold: out[l*1024 + (z?512:0) + n] = sum_k b[l][k] * W[l][k][n] ----------
__global__ __launch_bounds__(256)
void bfold(const float* __restrict__ b, const float* __restrict__ Wq,
           const float* __restrict__ Wk, float* __restrict__ out)
{
    const int n = blockIdx.x * 256 + threadIdx.x;   // grid (2, 6, 2)
    const int l = blockIdx.y, sel = blockIdx.z;
    const float* bb = b + l * 512;
    const float* W = (sel ? Wk : Wq) + (size_t)l * 512 * 512;
    float s = 0.f;
    for (int k = 0; k < 512; ++k) s += bb[k] * W[(size_t)k * 512 + n];
    out[l * 1024 + sel * 512 + n] = s;
}

// ---------- GEMM v6: counted-vmcnt depth-2, XCD swizzle, split-K, fused V-transpose ----------
// C[M,N] = A[M,K] @ BT[N,K]^T.
// PARTIAL: blockIdx.y selects K-chunk, writes f32 partials to outp + y*M*N.
// OUT_VT: 1 = all cols scatter to vt[bh][d][n]; 2 = cols >= 1024 scatter, rest normal.
template<int BM, int BN, int NWR, int NWC, int MINW,
         int HAS_BIAS, int HAS_RESID, int DO_GELU, int OUT_BF16, int PARTIAL, int OUT_VT>
__global__ __launch_bounds__(NWR * NWC * 64, MINW)
void gemm6(const uint16_t* __restrict__ A, const uint16_t* __restrict__ BT,
           const float* __restrict__ bias, const float* __restrict__ resid,
           void* __restrict__ outp, uint16_t* __restrict__ vt,
           int M, int N, int K, int kh)
{
    constexpr int NT = NWR * NWC * 64;
    constexpr int WM = BM / NWR, WN = BN / NWC;
    constexpr int FM = WM / 16, FN = WN / 16;
    constexpr int ASLOTS = 8 * BM, BSLOTS = 8 * BN, TOT = ASLOTS + BSLOTS;
    constexpr int S = TOT / NT;
    static_assert(S == 4, "vmcnt literal assumes S==4");
    __shared__ uint16_t As[2][ASLOTS * 8];
    __shared__ uint16_t Bs[2][BSLOTS * 8];
    const int tid = threadIdx.x, lane = tid & 63;
    const int w = tid >> 6, wr = w / NWC, wc = w % NWC;
    const int kg = lane >> 4, lr = lane & 15;
    const int nwg = gridDim.x;
    const int id0 = blockIdx.x;
    const int id = (id0 & 7) * (nwg >> 3) + (id0 >> 3);
    const int nbn = N / BN;
    const size_t m0 = (size_t)(id / nbn) * BM;
    const size_t n0 = (size_t)(id % nbn) * BN;
    const int kbase = PARTIAL ? blockIdx.y * kh : 0;

    auto stage = [&](int b, int k0) {
#pragma unroll
        for (int j = 0; j < S; ++j) {
            const int s = j * NT + tid;
            if (s < ASLOTS) {
                const int sub = s / BM, row = s % BM;
                async_lds16(A + (m0 + row) * K + k0 + sub * 8, &As[b][s * 8]);
            } else {
                const int s2 = s - ASLOTS;
                const int sub = s2 / BN, row = s2 % BN;
                async_lds16(BT + (n0 + row) * K + k0 + sub * 8, &Bs[b][s2 * 8]);
            }
        }
    };

    f32x4 acc[FM][FN] = {};
    const int nt = kh / 64;
    stage(0, kbase);
    stage(1, kbase + 64);
    int cur = 0;
    for (int t = 0; t < nt; ++t) {
        if (t < nt - 1) wait_vmcnt<S>(); else wait_vmcnt<0>();
        SBAR;
        s16x8 af[2][FM], bf[2][FN];
#pragma unroll
        for (int ks = 0; ks < 2; ++ks) {
#pragma unroll
            for (int i = 0; i < FM; ++i)
                af[ks][i] = *(const s16x8*)&As[cur][((ks * 4 + kg) * BM + wr * WM + i * 16 + lr) * 8];
#pragma unroll
            for (int j = 0; j < FN; ++j)
                bf[ks][j] = *(const s16x8*)&Bs[cur][((ks * 4 + kg) * BN + wc * WN + j * 16 + lr) * 8];
        }
        __builtin_amdgcn_s_setprio(1);
#pragma unroll
        for (int ks = 0; ks < 2; ++ks)
#pragma unroll
            for (int i = 0; i < FM; ++i)
#pragma unroll
                for (int j = 0; j < FN; ++j)
                    acc[i][j] = mfma16(af[ks][i], bf[ks][j], acc[i][j]);
        __builtin_amdgcn_s_setprio(0);
        LGKM0; SCHED0;
        SBAR;
        if (t + 2 < nt) stage(cur, kbase + (t + 2) * 64);
        cur ^= 1;
    }
    // ---- epilogue ----
    if (OUT_VT == 1 || (OUT_VT == 2 && n0 >= 1024)) {
        // scatter into per-head transposed layout vt[b*8+h][d][n] (bf16, n-stride 1)
#pragma unroll
        for (int i = 0; i < FM; ++i) {
            const size_t rbase = m0 + wr * WM + i * 16 + kg * 4;
            const int b = (int)(rbase >> 10), nloc = (int)(rbase & 1023);
#pragma unroll
            for (int j = 0; j < FN; ++j) {
                const int col = (int)n0 + wc * WN + j * 16 + lr;
                const int c2 = (OUT_VT == 2) ? col - 1024 : col;
                const float bval = HAS_BIAS ? bias[c2] : 0.0f;
                const int h = c2 >> 6, d = c2 & 63;
                ushort4 pk;
                pk.x = f2bf(acc[i][j][0] + bval);
                pk.y = f2bf(acc[i][j][1] + bval);
                pk.z = f2bf(acc[i][j][2] + bval);
                pk.w = f2bf(acc[i][j][3] + bval);
                *(ushort4*)&vt[((size_t)(b * 8 + h) * 64 + d) * 1024 + nloc] = pk;
            }
        }
        return;
    }
    float* pout = PARTIAL ? (float*)outp + (size_t)blockIdx.y * M * (size_t)N : nullptr;
#pragma unroll
    for (int i = 0; i < FM; ++i) {
        const size_t rbase = m0 + wr * WM + i * 16 + kg * 4;
#pragma unroll
        for (int j = 0; j < FN; ++j) {
            const size_t col = n0 + wc * WN + j * 16 + lr;
            const float bval = HAS_BIAS ? bias[col] : 0.0f;
#pragma unroll
            for (int r = 0; r < 4; ++r) {
                const size_t row = rbase + r;
                float v = acc[i][j][r] + bval;
                if (PARTIAL) { pout[row * (size_t)N + col] = v; continue; }
                if (DO_GELU)  v = gelu_exact(v);
                if (HAS_RESID) v += resid[row * (size_t)N + col];
                if (OUT_BF16) ((uint16_t*)outp)[row * (size_t)N + col] = f2bf(v);
                else          ((float*)outp)[row * (size_t)N + col] = v;
            }
        }
    }
}

// ---------- fused split-K reduce + residual + (optional) LayerNorm ----------
// x[row] += p0[row]+p1[row]+bias ; if DO_LN: xn[row] = LN(x[row]; sc,bi)
template<int DO_LN>
__global__ __launch_bounds__(256)
void reduce_ln(const float* __restrict__ p, const float* __restrict__ bias,
               float* __restrict__ x, const float* __restrict__ sc,
               const float* __restrict__ bi, uint16_t* __restrict__ xn)
{
    const int lane = threadIdx.x & 63;
    const size_t row = (size_t)blockIdx.x * 4 + (threadIdx.x >> 6);
    const int c = lane * 8;
    const size_t off = row * 512 + c;
    const float* p0 = p + off;
    const float* p1 = p + 4096ull * 512 + off;
    float4 a0 = *(const float4*)p0,        a1 = *(const float4*)(p0 + 4);
    float4 b0 = *(const float4*)p1,        b1 = *(const float4*)(p1 + 4);
    float4 s0 = *(const float4*)(bias + c), s1 = *(const float4*)(bias + c + 4);
    float4 r0 = *(const float4*)(x + off), r1 = *(const float4*)(x + off + 4);
    float v[8];
    v[0] = a0.x + b0.x + s0.x + r0.x;  v[1] = a0.y + b0.y + s0.y + r0.y;
    v[2] = a0.z + b0.z + s0.z + r0.z;  v[3] = a0.w + b0.w + s0.w + r0.w;
    v[4] = a1.x + b1.x + s1.x + r1.x;  v[5] = a1.y + b1.y + s1.y + r1.y;
    v[6] = a1.z + b1.z + s1.z + r1.z;  v[7] = a1.w + b1.w + s1.w + r1.w;
    *(float4*)(x + off)     = make_float4(v[0], v[1], v[2], v[3]);
    *(float4*)(x + off + 4) = make_float4(v[4], v[5], v[6], v[7]);
    if (DO_LN) {
        float s = 0.f, sq = 0.f;
#pragma unroll
        for (int j = 0; j < 8; ++j) { s += v[j]; sq += v[j] * v[j]; }
#pragma unroll
        for (int o = 1; o < 64; o <<= 1) { s += __shfl_xor(s, o); sq += __shfl_xor(sq, o); }
        const float mean = s * (1.0f / 512.0f);
        const float var  = sq * (1.0f / 512.0f) - mean * mean;
        const float rstd = rsqrtf(var + 1e-5f);
        uint16_t o8[8];
#pragma unroll
        for (int j = 0; j < 8; ++j)
            o8[j] = f2bf((v[j] - mean) * rstd * sc[c + j] + bi[c + j]);
        uint4 pk;
        pk.x = (uint32_t)o8[0] | ((uint32_t)o8[1] << 16);
        pk.y = (uint32_t)o8[2] | ((uint32_t)o8[3] << 16);
        pk.z = (uint32_t)o8[4] | ((uint32_t)o8[5] << 16);
        pk.w = (uint32_t)o8[6] | ((uint32_t)o8[7] << 16);
        *reinterpret_cast<uint4*>(xn + off) = pk;
    }
}

// ---------- flash attention: no-max softmax, fragment-ordered LDS, 1 barrier/tile ----------
__global__ __launch_bounds__(256)
void attn_flash(const uint16_t* __restrict__ Qb, const uint16_t* __restrict__ Kb,
                const uint16_t* __restrict__ Vt, uint16_t* __restrict__ Ob,
                int qstride, int kstride, int qoff, int koff)
{
    __shared__ uint16_t Ks[2][4096];   // [sub=d/8 8][kv 64][8] fragment-ordered
    __shared__ uint16_t Vs[2][4096];   // [sub=kv/8 8][d 64][8] fragment-ordered
    __shared__ uint16_t Pb[4][1024];   // per-wave [sub=kv/8 8][qrow 16][8]
    const int tid = threadIdx.x, lane = tid & 63, w = tid >> 6;
    const int kg = lane >> 4, lr = lane & 15;
    const int bh = blockIdx.y, b = bh >> 3, h = bh & 7;
    const int q0 = blockIdx.x * 64;
    const float CEXP = 0.125f * 1.44269504f;

    s16x8 aq0, aq1;
    {
        const size_t qrow = (size_t)b * 1024 + q0 + w * 16 + lr;
        const uint16_t* qp = Qb + qrow * qstride + qoff + h * 64 + kg * 8;
        aq0 = *(const s16x8*)qp;
        aq1 = *(const s16x8*)(qp + 32);
    }
    const uint16_t* kbase = Kb + (size_t)b * 1024 * kstride + koff + h * 64;
    const uint16_t* vbase = Vt + (size_t)bh * 65536;

    float l_r[4] = {0.f, 0.f, 0.f, 0.f};
    f32x4 acc[4] = {};

    auto stage = [&](int buf, int kv0) {
#pragma unroll
        for (int j = 0; j < 2; ++j) {
            const int s = j * 256 + tid;
            const int sub = s >> 6, row = s & 63;
            async_lds16(kbase + (size_t)(kv0 + row) * kstride + sub * 8, &Ks[buf][s * 8]);
            async_lds16(vbase + (size_t)row * 1024 + kv0 + sub * 8,      &Vs[buf][s * 8]);
        }
    };

    stage(0, 0);
    __syncthreads();
    int cur = 0;
    for (int t = 0; t < 16; ++t) {
        if (t < 15) stage(cur ^ 1, (t + 1) * 64);
        f32x4 s4[4];
        __builtin_amdgcn_s_setprio(1);
#pragma unroll
        for (int ni = 0; ni < 4; ++ni) {
            s16x8 bk0 = *(const s16x8*)&Ks[cur][(kg * 64 + ni * 16 + lr) * 8];
            s16x8 bk1 = *(const s16x8*)&Ks[cur][((4 + kg) * 64 + ni * 16 + lr) * 8];
            f32x4 z = {};
            z = mfma16(aq0, bk0, z);
            z = mfma16(aq1, bk1, z);
            s4[ni] = z;
        }
        __builtin_amdgcn_s_setprio(0);
#pragma unroll
        for (int ni = 0; ni < 4; ++ni) {
            const int slotb = (ni * 2 + (lr >> 3)) * 16 + kg * 4;
#pragma unroll
            for (int r = 0; r < 4; ++r) {
                const float pe = __builtin_amdgcn_exp2f(s4[ni][r] * CEXP);
                l_r[r] += pe;
                Pb[w][(slotb + r) * 8 + (lr & 7)] = f2bf(pe);
            }
        }
        s16x8 ap0 = *(const s16x8*)&Pb[w][(kg * 16 + lr) * 8];
        s16x8 ap1 = *(const s16x8*)&Pb[w][((4 + kg) * 16 + lr) * 8];
        __builtin_amdgcn_s_setprio(1);
#pragma unroll
        for (int ni = 0; ni < 4; ++ni) {
            s16x8 bv0 = *(const s16x8*)&Vs[cur][(kg * 64 + ni * 16 + lr) * 8];
            s16x8 bv1 = *(const s16x8*)&Vs[cur][((4 + kg) * 64 + ni * 16 + lr) * 8];
            acc[ni] = mfma16(ap0, bv0, acc[ni]);
            acc[ni] = mfma16(ap1, bv1, acc[ni]);
        }
        __builtin_amdgcn_s_setprio(0);
        __syncthreads();
        cur ^= 1;
    }
    float linv[4];
#pragma unroll
    for (int r = 0; r < 4; ++r) {
        float l = l_r[r];
        l += __shfl_xor(l, 1); l += __shfl_xor(l, 2);
        l += __shfl_xor(l, 4); l += __shfl_xor(l, 8);
        linv[r] = 1.0f / l;
    }
#pragma unroll
    for (int ni = 0; ni < 4; ++ni)
#pragma unroll
        for (int r = 0; r < 4; ++r) {
            const float v = acc[ni][r] * linv[r];
            const size_t row = (size_t)b * 1024 + q0 + w * 16 + kg * 4 + r;
            Ob[row * 512 + h * 64 + ni * 16 + lr] = f2bf(v);
        }
}

// ---------- host ----------
extern "C" void kernel_launch(void* const* d_in, const int* in_sizes, int n_in,
                              void* d_out, int out_size, void* d_ws, size_t ws_size,
                              hipStream_t stream)
{
    (void)in_sizes; (void)n_in; (void)out_size; (void)ws_size;
    const float* g     = (const float*)d_in[0];
    const float* x0    = (const float*)d_in[1];
    const float* ln1_s = (const float*)d_in[2];
    const float* ln1_b = (const float*)d_in[3];
    const float* Wqkv  = (const float*)d_in[4];
    const float* Wo_sa = (const float*)d_in[5];
    const float* bo_sa = (const float*)d_in[6];
    const float* lng_s = (const float*)d_in[7];
    const float* lng_b = (const float*)d_in[8];
    const float* lnx_s = (const float*)d_in[9];
    const float* lnx_b = (const float*)d_in[10];
    const float* Wq    = (const float*)d_in[11];
    const float* Wk    = (const float*)d_in[12];
    const float* Wv    = (const float*)d_in[13];
    const float* bv    = (const float*)d_in[14];
    const float* Wo_ca = (const float*)d_in[15];
    const float* bo_ca = (const float*)d_in[16];
    const float* lnf_s = (const float*)d_in[17];
    const float* lnf_b = (const float*)d_in[18];
    const float* W1    = (const float*)d_in[19];
    const float* b1    = (const float*)d_in[20];
    const float* W2    = (const float*)d_in[21];
    const float* b2    = (const float*)d_in[22];

    float* x = (float*)d_out;  // running residual stream (f32)

    char* p = (char*)d_ws;
    auto carve = [&](size_t n) { char* r = p; p += (n + 255) & ~(size_t)255; return r; };
    uint16_t* WqkT  = (uint16_t*)carve(6ull * 1024 * 512 * 2);  // scaled [l][WqT|WkT][512]
    uint16_t* WvT   = (uint16_t*)carve(6ull * 512 * 512 * 2);
    uint16_t* WocaT = (uint16_t*)carve(6ull * 512 * 512 * 2);
    uint16_t* WqkvT = (uint16_t*)carve(6ull * 1536 * 512 * 2);
    uint16_t* WosaT = (uint16_t*)carve(6ull * 512 * 512 * 2);
    uint16_t* W1T   = (uint16_t*)carve(6ull * 2048 * 512 * 2);
    uint16_t* W2T   = (uint16_t*)carve(6ull * 512 * 2048 * 2);
    float*    bqk   = (float*)carve(6144ull * 4);               // folded LN-bias @ W
    uint16_t* zg    = (uint16_t*)carve(4096ull * 512 * 2);      // standardized g
    uint16_t* qkall = (uint16_t*)carve(4096ull * 6144 * 2);     // all layers' Q|K
    uint16_t* xn    = (uint16_t*)carve(4096ull * 512 * 2);
    uint16_t* qkvu  = (uint16_t*)carve(4096ull * 1536 * 2);
    uint16_t* vt    = (uint16_t*)carve(32ull * 64 * 1024 * 2);
    uint16_t* ab    = (uint16_t*)carve(4096ull * 512 * 2);
    uint16_t* hb    = (uint16_t*)carve(4096ull * 2048 * 2);
    float*    pk2   = (float*)carve(2ull * 4096 * 512 * 4);     // split-K partials

    // ---- prep: weights (QK scale-folded), bias fold ----
    dim3 tb(32, 8);
    wtrans<<<dim3(16, 16, 6), tb, 0, stream>>>(Wq,    WqkT,  512, 512,  1024ull * 512, 0,   lng_s);
    wtrans<<<dim3(16, 16, 6), tb, 0, stream>>>(Wk,    WqkT,  512, 512,  1024ull * 512, 512, lng_s);
    wtrans<<<dim3(16, 16, 6), tb, 0, stream>>>(Wv,    WvT,   512, 512,  512ull * 512, 0, nullptr);
    wtrans<<<dim3(16, 16, 6), tb, 0, stream>>>(Wo_ca, WocaT, 512, 512,  512ull * 512, 0, nullptr);
    wtrans<<<dim3(16, 48, 6), tb, 0, stream>>>(Wqkv,  WqkvT, 512, 1536, 1536ull * 512, 0, nullptr);
    wtrans<<<dim3(16, 16, 6), tb, 0, stream>>>(Wo_sa, WosaT, 512, 512,  512ull * 512, 0, nullptr);
    wtrans<<<dim3(16, 64, 6), tb, 0, stream>>>(W1,    W1T,   512, 2048, 2048ull * 512, 0, nullptr);
    wtrans<<<dim3(64, 16, 6), tb, 0, stream>>>(W2,    W2T,   2048, 512, 2048ull * 512, 0, nullptr);
    bfold<<<dim3(2, 6, 2), 256, 0, stream>>>(lng_b, Wq, Wk, bqk);

    hipMemcpyAsync(x, x0, 4096ull * 512 * 4, hipMemcpyDeviceToDevice, stream);

    // ---- hoisted Q/K for all layers: qkall = z(g) @ WqkT + bqk ----
    ln_t<0><<<1024, 256, 0, stream>>>(g, nullptr, nullptr, zg);
    ln_t<1><<<1024, 256, 0, stream>>>(x, lnx_s, lnx_b, xn);   // lnx layer 0
    gemm6<128, 128, 2, 4, 4, 1, 0, 0, 1, 0, 0><<<1536, 512, 0, stream>>>(
        zg, WqkT, bqk, nullptr, qkall, nullptr, 4096, 6144, 512, 512);

    const dim3 ga(16, 32);

    for (int l = 0; l < 6; ++l) {
        const size_t o512 = (size_t)l * 512, oW = (size_t)l * 512 * 512;
        const size_t oW1 = (size_t)l * 2048 * 512, oWqkv = (size_t)l * 1536 * 512;
        const size_t o2048 = (size_t)l * 2048;

        // ---- relational cross attention (Q,K precomputed) ----
        gemm6<64, 64, 2, 2, 4, 1, 0, 0, 0, 0, 1><<<512, 256, 0, stream>>>(
            xn, WvT + oW, bv + o512, nullptr, nullptr, vt, 4096, 512, 512, 512);
        attn_flash<<<ga, 256, 0, stream>>>(qkall, qkall, vt, ab, 6144, 6144,
                                           l * 1024, l * 1024 + 512);
        gemm6<64, 64, 2, 2, 4, 1, 1, 0, 0, 0, 0><<<512, 256, 0, stream>>>(
            ab, WocaT + oW, bo_ca + o512, x, x, nullptr, 4096, 512, 512, 512);

        // ---- feed-forward 1 ----
        ln_t<1><<<1024, 256, 0, stream>>>(x, lnf_s + o512, lnf_b + o512, xn);
        gemm6<128, 128, 2, 4, 4, 1, 0, 1, 1, 0, 0><<<512, 512, 0, stream>>>(
            xn, W1T + oW1, b1 + o2048, nullptr, hb, nullptr, 4096, 2048, 512, 512);
        gemm6<64, 64, 2, 2, 4, 0, 0, 0, 0, 1, 0><<<dim3(512, 2), 256, 0, stream>>>(
            hb, W2T + oW1, nullptr, nullptr, pk2, nullptr, 4096, 512, 2048, 1024);
        reduce_ln<1><<<1024, 256, 0, stream>>>(pk2, b2 + o512, x,
                                               ln1_s + o512, ln1_b + o512, xn);

        // ---- pre-norm self attention ----
        gemm6<128, 128, 2, 4, 4, 0, 0, 0, 1, 0, 2><<<384, 512, 0, stream>>>(
            xn, WqkvT + oWqkv, nullptr, nullptr, qkvu, vt, 4096, 1536, 512, 512);
        attn_flash<<<ga, 256, 0, stream>>>(qkvu, qkvu, vt, ab, 1536, 1536, 0, 512);
        gemm6<64, 64, 2, 2, 4, 1, 1, 0, 0, 0, 0><<<512, 256, 0, stream>>>(
            ab, WosaT + oW, bo_sa + o512, x, x, nullptr, 4096, 512, 512, 512);

        // ---- feed-forward 2 ----
        ln_t<1><<<1024, 256, 0, stream>>>(x, lnf_s + o512, lnf_b + o512, xn);
        gemm6<128, 128, 2, 4, 4, 1, 0, 1, 1, 0, 0><<<512, 512, 0, stream>>>(
            xn, W1T + oW1, b1 + o2048, nullptr, hb, nullptr, 4096, 2048, 512, 512);
        gemm6<64, 64, 2, 2, 4, 0, 0, 0, 0, 1, 0><<<dim3(512, 2), 256, 0, stream>>>(
            hb, W2T + oW1, nullptr, nullptr, pk2, nullptr, 4096, 512, 2048, 1024);
        if (l < 5)
            reduce_ln<1><<<1024, 256, 0, stream>>>(pk2, b2 + o512, x,
                                                   lnx_s + o512 + 512, lnx_b + o512 + 512, xn);
        else
            reduce_ln<0><<<1024, 256, 0, stream>>>(pk2, b2 + o512, x,
                                                   nullptr, nullptr, nullptr);
    }
}

// Round 8
// 1590.967 us; speedup vs baseline: 1.1477x; 1.0365x over previous
//
#include <hip/hip_runtime.h>
#include <hip/hip_bf16.h>
#include <cstdint>
#include <cstddef>

#define DEV __device__ __forceinline__

using f32x4 = __attribute__((ext_vector_type(4))) float;
using bfx8  = __attribute__((ext_vector_type(8))) __bf16;
using s16x8 = __attribute__((ext_vector_type(8))) short;

// ---------- helpers ----------
DEV uint16_t f2bf(float f) {
    union { float f; uint32_t u; } x; x.f = f;
    uint32_t r = x.u + 0x7fffu + ((x.u >> 16) & 1u);   // RNE
    return (uint16_t)(r >> 16);
}

DEV float gelu_exact(float v) {
    return 0.5f * v * (1.0f + erff(v * 0.70710678118654752f));
}

DEV f32x4 mfma16(s16x8 a, s16x8 b, f32x4 c) {
    return __builtin_amdgcn_mfma_f32_16x16x32_bf16(
        __builtin_bit_cast(bfx8, a), __builtin_bit_cast(bfx8, b), c, 0, 0, 0);
}

DEV void async_lds16(const void* g, void* l) {
    __builtin_amdgcn_global_load_lds(
        (const __attribute__((address_space(1))) uint32_t*)g,
        (__attribute__((address_space(3))) uint32_t*)l, 16, 0, 0);
}

template<int N> DEV void wait_vmcnt() {
    if constexpr (N == 0)      asm volatile("s_waitcnt vmcnt(0)" ::: "memory");
    else if constexpr (N == 4) asm volatile("s_waitcnt vmcnt(4)" ::: "memory");
    else static_assert(N == 0 || N == 4, "add vmcnt literal");
}
#define SBAR      asm volatile("s_barrier" ::: "memory")
#define LGKM0     asm volatile("s_waitcnt lgkmcnt(0)" ::: "memory")
#define SCHED0    __builtin_amdgcn_sched_barrier(0)

// ---------- LayerNorm: f32 [rows,512] -> bf16 (optional scale/bias), one wave/row ----------
template<int HAS_SB>
__global__ __launch_bounds__(256)
void ln_t(const float* __restrict__ in, const float* __restrict__ sc,
          const float* __restrict__ bi, uint16_t* __restrict__ out)
{
    const int lane = threadIdx.x & 63;
    const size_t row = (size_t)blockIdx.x * 4 + (threadIdx.x >> 6);
    const float* p = in + row * 512 + lane * 8;
    float4 a = *(const float4*)p;
    float4 b4 = *(const float4*)(p + 4);
    float v[8] = {a.x, a.y, a.z, a.w, b4.x, b4.y, b4.z, b4.w};
    float s = 0.f, sq = 0.f;
#pragma unroll
    for (int j = 0; j < 8; ++j) { s += v[j]; sq += v[j] * v[j]; }
#pragma unroll
    for (int o = 1; o < 64; o <<= 1) { s += __shfl_xor(s, o); sq += __shfl_xor(sq, o); }
    const float mean = s * (1.0f / 512.0f);
    const float var  = sq * (1.0f / 512.0f) - mean * mean;
    const float rstd = rsqrtf(var + 1e-5f);
    const int c = lane * 8;
    uint16_t o8[8];
#pragma unroll
    for (int j = 0; j < 8; ++j) {
        float z = (v[j] - mean) * rstd;
        if (HAS_SB) z = z * sc[c + j] + bi[c + j];
        o8[j] = f2bf(z);
    }
    uint4 pk;
    pk.x = (uint32_t)o8[0] | ((uint32_t)o8[1] << 16);
    pk.y = (uint32_t)o8[2] | ((uint32_t)o8[3] << 16);
    pk.z = (uint32_t)o8[4] | ((uint32_t)o8[5] << 16);
    pk.w = (uint32_t)o8[6] | ((uint32_t)o8[7] << 16);
    *reinterpret_cast<uint4*>(out + row * 512 + c) = pk;
}

// ---------- weight transpose-convert: f32 [L][K][N] -> bf16 [L][row0+N][K], opt row-scale ----------
__global__ __launch_bounds__(256)
void wtrans(const float* __restrict__ W, uint16_t* __restrict__ WT, int K, int N,
            size_t lstride, int row0, const float* __restrict__ kscale)
{
    __shared__ float tile[32][33];
    const int l = blockIdx.z;
    const int k0 = blockIdx.x * 32, n0 = blockIdx.y * 32;
    const float* Wl = W + (size_t)l * K * N;
    uint16_t* WTl = WT + (size_t)l * lstride;
    const int tx = threadIdx.x, ty = threadIdx.y;  // (32,8)
#pragma unroll
    for (int j = 0; j < 4; ++j) {
        const int k = k0 + ty + j * 8;
        float w = Wl[(size_t)k * N + n0 + tx];
        if (kscale) w *= kscale[l * K + k];
        tile[ty + j * 8][tx] = w;
    }
    __syncthreads();
#pragma unroll
    for (int j = 0; j < 4; ++j)
        WTl[(size_t)(row0 + n0 + ty + j * 8) * K + k0 + tx] = f2bf(tile[tx][ty + j * 8]);
}

// ---------- bias fold: out[l*1024 + (z?512:0) + n] = sum_k b[l][k] * W[l][k][n] ----------
__global__ __launch_bounds__(256)
void bfold(const float* __restrict__ b, const float* __restrict__ Wq,
           const float* __restrict__ Wk, float* __restrict__ out)
{
    const int n = blockIdx.x * 256 + threadIdx.x;   // grid (2, 6, 2)
    const int l = blockIdx.y, sel = blockIdx.z;
    const float* bb = b + l * 512;
    const float* W = (sel ? Wk : Wq) + (size_t)l * 512 * 512;
    float s = 0.f;
    for (int k = 0; k < 512; ++k) s += bb[k] * W[(size_t)k * 512 + n];
    out[l * 1024 + sel * 512 + n] = s;
}

// ---------- GEMM v7: counted-vmcnt depth-2, 2D-rect XCD swizzle, fused epilogues ----------
// C[M,N] = A[M,K] @ BT[N,K]^T. Requires (M/BM)%2==0, (N/BN)%4==0.
// OUT_VT: 1 = all cols scatter to vt[bh][d][n]; 2 = cols >= 1024 scatter, rest normal.
template<int BM, int BN, int NWR, int NWC, int MINW,
         int HAS_BIAS, int HAS_RESID, int DO_GELU, int OUT_BF16, int OUT_VT>
__global__ __launch_bounds__(NWR * NWC * 64, MINW)
void gemm7(const uint16_t* __restrict__ A, const uint16_t* __restrict__ BT,
           const float* __restrict__ bias, const float* __restrict__ resid,
           void* __restrict__ outp, uint16_t* __restrict__ vt,
           int M, int N, int K)
{
    constexpr int NT = NWR * NWC * 64;
    constexpr int WM = BM / NWR, WN = BN / NWC;
    constexpr int FM = WM / 16, FN = WN / 16;
    constexpr int ASLOTS = 8 * BM, BSLOTS = 8 * BN, TOT = ASLOTS + BSLOTS;
    constexpr int S = TOT / NT;
    static_assert(S == 4, "vmcnt literal assumes S==4");
    __shared__ uint16_t As[2][ASLOTS * 8];
    __shared__ uint16_t Bs[2][BSLOTS * 8];
    const int tid = threadIdx.x, lane = tid & 63;
    const int w = tid >> 6, wr = w / NWC, wc = w % NWC;
    const int kg = lane >> 4, lr = lane & 15;
    // 2D-rectangle XCD swizzle: each XCD owns an (nbm/2)x(nbn/4) tile rectangle,
    // minimizing per-XCD L2 working set (A-rows + B-cols duplication across XCDs).
    const int nbn = N / BN, nbm = M / BM;
    const int rect_m = nbm >> 1, rect_n = nbn >> 2;
    const int xcd = blockIdx.x & 7, c = blockIdx.x >> 3;
    const int bm = (xcd >> 2) * rect_m + c / rect_n;
    const int bn = (xcd & 3) * rect_n + c % rect_n;
    const size_t m0 = (size_t)bm * BM;
    const size_t n0 = (size_t)bn * BN;

    auto stage = [&](int b, int k0) {
#pragma unroll
        for (int j = 0; j < S; ++j) {
            const int s = j * NT + tid;
            if (s < ASLOTS) {
                const int sub = s / BM, row = s % BM;
                async_lds16(A + (m0 + row) * K + k0 + sub * 8, &As[b][s * 8]);
            } else {
                const int s2 = s - ASLOTS;
                const int sub = s2 / BN, row = s2 % BN;
                async_lds16(BT + (n0 + row) * K + k0 + sub * 8, &Bs[b][s2 * 8]);
            }
        }
    };

    f32x4 acc[FM][FN] = {};
    const int nt = K / 64;
    stage(0, 0);
    stage(1, 64);
    int cur = 0;
    for (int t = 0; t < nt; ++t) {
        if (t < nt - 1) wait_vmcnt<S>(); else wait_vmcnt<0>();
        SBAR;
        s16x8 af[2][FM], bf[2][FN];
#pragma unroll
        for (int ks = 0; ks < 2; ++ks) {
#pragma unroll
            for (int i = 0; i < FM; ++i)
                af[ks][i] = *(const s16x8*)&As[cur][((ks * 4 + kg) * BM + wr * WM + i * 16 + lr) * 8];
#pragma unroll
            for (int j = 0; j < FN; ++j)
                bf[ks][j] = *(const s16x8*)&Bs[cur][((ks * 4 + kg) * BN + wc * WN + j * 16 + lr) * 8];
        }
        __builtin_amdgcn_s_setprio(1);
#pragma unroll
        for (int ks = 0; ks < 2; ++ks)
#pragma unroll
            for (int i = 0; i < FM; ++i)
#pragma unroll
                for (int j = 0; j < FN; ++j)
                    acc[i][j] = mfma16(af[ks][i], bf[ks][j], acc[i][j]);
        __builtin_amdgcn_s_setprio(0);
        LGKM0; SCHED0;
        SBAR;
        if (t + 2 < nt) stage(cur, (t + 2) * 64);
        cur ^= 1;
    }
    // ---- epilogue ----
    if (OUT_VT == 1 || (OUT_VT == 2 && n0 >= 1024)) {
        // scatter into per-head transposed layout vt[b*8+h][d][n] (bf16, n-stride 1)
#pragma unroll
        for (int i = 0; i < FM; ++i) {
            const size_t rbase = m0 + wr * WM + i * 16 + kg * 4;
            const int b = (int)(rbase >> 10), nloc = (int)(rbase & 1023);
#pragma unroll
            for (int j = 0; j < FN; ++j) {
                const int col = (int)n0 + wc * WN + j * 16 + lr;
                const int c2 = (OUT_VT == 2) ? col - 1024 : col;
                const float bval = HAS_BIAS ? bias[c2] : 0.0f;
                const int h = c2 >> 6, d = c2 & 63;
                ushort4 pk;
                pk.x = f2bf(acc[i][j][0] + bval);
                pk.y = f2bf(acc[i][j][1] + bval);
                pk.z = f2bf(acc[i][j][2] + bval);
                pk.w = f2bf(acc[i][j][3] + bval);
                *(ushort4*)&vt[((size_t)(b * 8 + h) * 64 + d) * 1024 + nloc] = pk;
            }
        }
        return;
    }
#pragma unroll
    for (int i = 0; i < FM; ++i) {
        const size_t rbase = m0 + wr * WM + i * 16 + kg * 4;
#pragma unroll
        for (int j = 0; j < FN; ++j) {
            const size_t col = n0 + wc * WN + j * 16 + lr;
            const float bval = HAS_BIAS ? bias[col] : 0.0f;
#pragma unroll
            for (int r = 0; r < 4; ++r) {
                const size_t row = rbase + r;
                float v = acc[i][j][r] + bval;
                if (DO_GELU)  v = gelu_exact(v);
                if (HAS_RESID) v += resid[row * (size_t)N + col];
                if (OUT_BF16) ((uint16_t*)outp)[row * (size_t)N + col] = f2bf(v);
                else          ((float*)outp)[row * (size_t)N + col] = v;
            }
        }
    }
}

// ---------- flash attention: no-max softmax, fragment-ordered LDS, 1 barrier/tile ----------
__global__ __launch_bounds__(256)
void attn_flash(const uint16_t* __restrict__ Qb, const uint16_t* __restrict__ Kb,
                const uint16_t* __restrict__ Vt, uint16_t* __restrict__ Ob,
                int qstride, int kstride, int qoff, int koff)
{
    __shared__ uint16_t Ks[2][4096];   // [sub=d/8 8][kv 64][8] fragment-ordered
    __shared__ uint16_t Vs[2][4096];   // [sub=kv/8 8][d 64][8] fragment-ordered
    __shared__ uint16_t Pb[4][1024];   // per-wave [sub=kv/8 8][qrow 16][8]
    const int tid = threadIdx.x, lane = tid & 63, w = tid >> 6;
    const int kg = lane >> 4, lr = lane & 15;
    const int bh = blockIdx.y, b = bh >> 3, h = bh & 7;
    const int q0 = blockIdx.x * 64;
    const float CEXP = 0.125f * 1.44269504f;

    s16x8 aq0, aq1;
    {
        const size_t qrow = (size_t)b * 1024 + q0 + w * 16 + lr;
        const uint16_t* qp = Qb + qrow * qstride + qoff + h * 64 + kg * 8;
        aq0 = *(const s16x8*)qp;
        aq1 = *(const s16x8*)(qp + 32);
    }
    const uint16_t* kbase = Kb + (size_t)b * 1024 * kstride + koff + h * 64;
    const uint16_t* vbase = Vt + (size_t)bh * 65536;

    float l_r[4] = {0.f, 0.f, 0.f, 0.f};
    f32x4 acc[4] = {};

    auto stage = [&](int buf, int kv0) {
#pragma unroll
        for (int j = 0; j < 2; ++j) {
            const int s = j * 256 + tid;
            const int sub = s >> 6, row = s & 63;
            async_lds16(kbase + (size_t)(kv0 + row) * kstride + sub * 8, &Ks[buf][s * 8]);
            async_lds16(vbase + (size_t)row * 1024 + kv0 + sub * 8,      &Vs[buf][s * 8]);
        }
    };

    stage(0, 0);
    __syncthreads();
    int cur = 0;
    for (int t = 0; t < 16; ++t) {
        if (t < 15) stage(cur ^ 1, (t + 1) * 64);
        f32x4 s4[4];
        __builtin_amdgcn_s_setprio(1);
#pragma unroll
        for (int ni = 0; ni < 4; ++ni) {
            s16x8 bk0 = *(const s16x8*)&Ks[cur][(kg * 64 + ni * 16 + lr) * 8];
            s16x8 bk1 = *(const s16x8*)&Ks[cur][((4 + kg) * 64 + ni * 16 + lr) * 8];
            f32x4 z = {};
            z = mfma16(aq0, bk0, z);
            z = mfma16(aq1, bk1, z);
            s4[ni] = z;
        }
        __builtin_amdgcn_s_setprio(0);
#pragma unroll
        for (int ni = 0; ni < 4; ++ni) {
            const int slotb = (ni * 2 + (lr >> 3)) * 16 + kg * 4;
#pragma unroll
            for (int r = 0; r < 4; ++r) {
                const float pe = __builtin_amdgcn_exp2f(s4[ni][r] * CEXP);
                l_r[r] += pe;
                Pb[w][(slotb + r) * 8 + (lr & 7)] = f2bf(pe);
            }
        }
        s16x8 ap0 = *(const s16x8*)&Pb[w][(kg * 16 + lr) * 8];
        s16x8 ap1 = *(const s16x8*)&Pb[w][((4 + kg) * 16 + lr) * 8];
        __builtin_amdgcn_s_setprio(1);
#pragma unroll
        for (int ni = 0; ni < 4; ++ni) {
            s16x8 bv0 = *(const s16x8*)&Vs[cur][(kg * 64 + ni * 16 + lr) * 8];
            s16x8 bv1 = *(const s16x8*)&Vs[cur][((4 + kg) * 64 + ni * 16 + lr) * 8];
            acc[ni] = mfma16(ap0, bv0, acc[ni]);
            acc[ni] = mfma16(ap1, bv1, acc[ni]);
        }
        __builtin_amdgcn_s_setprio(0);
        __syncthreads();
        cur ^= 1;
    }
    float linv[4];
#pragma unroll
    for (int r = 0; r < 4; ++r) {
        float l = l_r[r];
        l += __shfl_xor(l, 1); l += __shfl_xor(l, 2);
        l += __shfl_xor(l, 4); l += __shfl_xor(l, 8);
        linv[r] = 1.0f / l;
    }
#pragma unroll
    for (int ni = 0; ni < 4; ++ni)
#pragma unroll
        for (int r = 0; r < 4; ++r) {
            const float v = acc[ni][r] * linv[r];
            const size_t row = (size_t)b * 1024 + q0 + w * 16 + kg * 4 + r;
            Ob[row * 512 + h * 64 + ni * 16 + lr] = f2bf(v);
        }
}

// ---------- host ----------
extern "C" void kernel_launch(void* const* d_in, const int* in_sizes, int n_in,
                              void* d_out, int out_size, void* d_ws, size_t ws_size,
                              hipStream_t stream)
{
    (void)in_sizes; (void)n_in; (void)out_size; (void)ws_size;
    const float* g     = (const float*)d_in[0];
    const float* x0    = (const float*)d_in[1];
    const float* ln1_s = (const float*)d_in[2];
    const float* ln1_b = (const float*)d_in[3];
    const float* Wqkv  = (const float*)d_in[4];
    const float* Wo_sa = (const float*)d_in[5];
    const float* bo_sa = (const float*)d_in[6];
    const float* lng_s = (const float*)d_in[7];
    const float* lng_b = (const float*)d_in[8];
    const float* lnx_s = (const float*)d_in[9];
    const float* lnx_b = (const float*)d_in[10];
    const float* Wq    = (const float*)d_in[11];
    const float* Wk    = (const float*)d_in[12];
    const float* Wv    = (const float*)d_in[13];
    const float* bv    = (const float*)d_in[14];
    const float* Wo_ca = (const float*)d_in[15];
    const float* bo_ca = (const float*)d_in[16];
    const float* lnf_s = (const float*)d_in[17];
    const float* lnf_b = (const float*)d_in[18];
    const float* W1    = (const float*)d_in[19];
    const float* b1    = (const float*)d_in[20];
    const float* W2    = (const float*)d_in[21];
    const float* b2    = (const float*)d_in[22];

    float* x = (float*)d_out;  // running residual stream (f32)

    char* p = (char*)d_ws;
    auto carve = [&](size_t n) { char* r = p; p += (n + 255) & ~(size_t)255; return r; };
    uint16_t* WqkT  = (uint16_t*)carve(6ull * 1024 * 512 * 2);  // scaled [l][WqT|WkT][512]
    uint16_t* WvT   = (uint16_t*)carve(6ull * 512 * 512 * 2);
    uint16_t* WocaT = (uint16_t*)carve(6ull * 512 * 512 * 2);
    uint16_t* WqkvT = (uint16_t*)carve(6ull * 1536 * 512 * 2);
    uint16_t* WosaT = (uint16_t*)carve(6ull * 512 * 512 * 2);
    uint16_t* W1T   = (uint16_t*)carve(6ull * 2048 * 512 * 2);
    uint16_t* W2T   = (uint16_t*)carve(6ull * 512 * 2048 * 2);
    float*    bqk   = (float*)carve(6144ull * 4);               // folded LN-bias @ W
    uint16_t* zg    = (uint16_t*)carve(4096ull * 512 * 2);      // standardized g
    uint16_t* qkall = (uint16_t*)carve(4096ull * 6144 * 2);     // all layers' Q|K
    uint16_t* xn    = (uint16_t*)carve(4096ull * 512 * 2);
    uint16_t* qkvu  = (uint16_t*)carve(4096ull * 1536 * 2);
    uint16_t* vt    = (uint16_t*)carve(32ull * 64 * 1024 * 2);
    uint16_t* ab    = (uint16_t*)carve(4096ull * 512 * 2);
    uint16_t* hb    = (uint16_t*)carve(4096ull * 2048 * 2);

    // ---- prep: weights (QK scale-folded), bias fold ----
    dim3 tb(32, 8);
    wtrans<<<dim3(16, 16, 6), tb, 0, stream>>>(Wq,    WqkT,  512, 512,  1024ull * 512, 0,   lng_s);
    wtrans<<<dim3(16, 16, 6), tb, 0, stream>>>(Wk,    WqkT,  512, 512,  1024ull * 512, 512, lng_s);
    wtrans<<<dim3(16, 16, 6), tb, 0, stream>>>(Wv,    WvT,   512, 512,  512ull * 512, 0, nullptr);
    wtrans<<<dim3(16, 16, 6), tb, 0, stream>>>(Wo_ca, WocaT, 512, 512,  512ull * 512, 0, nullptr);
    wtrans<<<dim3(16, 48, 6), tb, 0, stream>>>(Wqkv,  WqkvT, 512, 1536, 1536ull * 512, 0, nullptr);
    wtrans<<<dim3(16, 16, 6), tb, 0, stream>>>(Wo_sa, WosaT, 512, 512,  512ull * 512, 0, nullptr);
    wtrans<<<dim3(16, 64, 6), tb, 0, stream>>>(W1,    W1T,   512, 2048, 2048ull * 512, 0, nullptr);
    wtrans<<<dim3(64, 16, 6), tb, 0, stream>>>(W2,    W2T,   2048, 512, 2048ull * 512, 0, nullptr);
    bfold<<<dim3(2, 6, 2), 256, 0, stream>>>(lng_b, Wq, Wk, bqk);

    hipMemcpyAsync(x, x0, 4096ull * 512 * 4, hipMemcpyDeviceToDevice, stream);

    // ---- hoisted Q/K for all layers: qkall = z(g) @ WqkT + bqk ----
    ln_t<0><<<1024, 256, 0, stream>>>(g, nullptr, nullptr, zg);
    ln_t<1><<<1024, 256, 0, stream>>>(x, lnx_s, lnx_b, xn);   // lnx layer 0
    gemm7<128, 128, 2, 4, 4, 1, 0, 0, 1, 0><<<1536, 512, 0, stream>>>(
        zg, WqkT, bqk, nullptr, qkall, nullptr, 4096, 6144, 512);

    const dim3 ga(16, 32);

    for (int l = 0; l < 6; ++l) {
        const size_t o512 = (size_t)l * 512, oW = (size_t)l * 512 * 512;
        const size_t oW1 = (size_t)l * 2048 * 512, oWqkv = (size_t)l * 1536 * 512;
        const size_t o2048 = (size_t)l * 2048;

        // ---- relational cross attention (Q,K precomputed) ----
        gemm7<64, 64, 2, 2, 4, 1, 0, 0, 0, 1><<<512, 256, 0, stream>>>(
            xn, WvT + oW, bv + o512, nullptr, nullptr, vt, 4096, 512, 512);
        attn_flash<<<ga, 256, 0, stream>>>(qkall, qkall, vt, ab, 6144, 6144,
                                           l * 1024, l * 1024 + 512);
        gemm7<64, 64, 2, 2, 4, 1, 1, 0, 0, 0><<<512, 256, 0, stream>>>(
            ab, WocaT + oW, bo_ca + o512, x, x, nullptr, 4096, 512, 512);

        // ---- feed-forward 1 ----
        ln_t<1><<<1024, 256, 0, stream>>>(x, lnf_s + o512, lnf_b + o512, xn);
        gemm7<128, 128, 2, 4, 4, 1, 0, 1, 1, 0><<<512, 512, 0, stream>>>(
            xn, W1T + oW1, b1 + o2048, nullptr, hb, nullptr, 4096, 2048, 512);
        gemm7<64, 64, 2, 2, 4, 1, 1, 0, 0, 0><<<512, 256, 0, stream>>>(
            hb, W2T + oW1, b2 + o512, x, x, nullptr, 4096, 512, 2048);
        ln_t<1><<<1024, 256, 0, stream>>>(x, ln1_s + o512, ln1_b + o512, xn);

        // ---- pre-norm self attention ----
        gemm7<128, 128, 2, 4, 4, 0, 0, 0, 1, 2><<<384, 512, 0, stream>>>(
            xn, WqkvT + oWqkv, nullptr, nullptr, qkvu, vt, 4096, 1536, 512);
        attn_flash<<<ga, 256, 0, stream>>>(qkvu, qkvu, vt, ab, 1536, 1536, 0, 512);
        gemm7<64, 64, 2, 2, 4, 1, 1, 0, 0, 0><<<512, 256, 0, stream>>>(
            ab, WosaT + oW, bo_sa + o512, x, x, nullptr, 4096, 512, 512);

        // ---- feed-forward 2 ----
        ln_t<1><<<1024, 256, 0, stream>>>(x, lnf_s + o512, lnf_b + o512, xn);
        gemm7<128, 128, 2, 4, 4, 1, 0, 1, 1, 0><<<512, 512, 0, stream>>>(
            xn, W1T + oW1, b1 + o2048, nullptr, hb, nullptr, 4096, 2048, 512);
        gemm7<64, 64, 2, 2, 4, 1, 1, 0, 0, 0><<<512, 256, 0, stream>>>(
            hb, W2T + oW1, b2 + o512, x, x, nullptr, 4096, 512, 2048);
        if (l < 5)
            ln_t<1><<<1024, 256, 0, stream>>>(x, lnx_s + o512 + 512, lnx_b + o512 + 512, xn);
    }
}

// Round 9
// 1578.476 us; speedup vs baseline: 1.1568x; 1.0079x over previous
//
#include <hip/hip_runtime.h>
#include <hip/hip_bf16.h>
#include <cstdint>
#include <cstddef>

#define DEV __device__ __forceinline__

using f32x4 = __attribute__((ext_vector_type(4))) float;
using bfx8  = __attribute__((ext_vector_type(8))) __bf16;
using s16x8 = __attribute__((ext_vector_type(8))) short;

// ---------- helpers ----------
DEV uint16_t f2bf(float f) {
    union { float f; uint32_t u; } x; x.f = f;
    uint32_t r = x.u + 0x7fffu + ((x.u >> 16) & 1u);   // RNE
    return (uint16_t)(r >> 16);
}

DEV float gelu_exact(float v) {
    return 0.5f * v * (1.0f + erff(v * 0.70710678118654752f));
}

DEV f32x4 mfma16(s16x8 a, s16x8 b, f32x4 c) {
    return __builtin_amdgcn_mfma_f32_16x16x32_bf16(
        __builtin_bit_cast(bfx8, a), __builtin_bit_cast(bfx8, b), c, 0, 0, 0);
}

DEV void async_lds16(const void* g, void* l) {
    __builtin_amdgcn_global_load_lds(
        (const __attribute__((address_space(1))) uint32_t*)g,
        (__attribute__((address_space(3))) uint32_t*)l, 16, 0, 0);
}

template<int N> DEV void wait_vmcnt() {
    if constexpr (N == 0)      asm volatile("s_waitcnt vmcnt(0)" ::: "memory");
    else if constexpr (N == 4) asm volatile("s_waitcnt vmcnt(4)" ::: "memory");
    else static_assert(N == 0 || N == 4, "add vmcnt literal");
}
#define SBAR      asm volatile("s_barrier" ::: "memory")
#define LGKM0     asm volatile("s_waitcnt lgkmcnt(0)" ::: "memory")
#define SCHED0    __builtin_amdgcn_sched_barrier(0)

// ---------- LayerNorm: f32 [rows,512] -> bf16 (optional scale/bias), one wave/row ----------
template<int HAS_SB>
__global__ __launch_bounds__(256)
void ln_t(const float* __restrict__ in, const float* __restrict__ sc,
          const float* __restrict__ bi, uint16_t* __restrict__ out)
{
    const int lane = threadIdx.x & 63;
    const size_t row = (size_t)blockIdx.x * 4 + (threadIdx.x >> 6);
    const float* p = in + row * 512 + lane * 8;
    float4 a = *(const float4*)p;
    float4 b4 = *(const float4*)(p + 4);
    float v[8] = {a.x, a.y, a.z, a.w, b4.x, b4.y, b4.z, b4.w};
    float s = 0.f, sq = 0.f;
#pragma unroll
    for (int j = 0; j < 8; ++j) { s += v[j]; sq += v[j] * v[j]; }
#pragma unroll
    for (int o = 1; o < 64; o <<= 1) { s += __shfl_xor(s, o); sq += __shfl_xor(sq, o); }
    const float mean = s * (1.0f / 512.0f);
    const float var  = sq * (1.0f / 512.0f) - mean * mean;
    const float rstd = rsqrtf(var + 1e-5f);
    const int c = lane * 8;
    uint16_t o8[8];
#pragma unroll
    for (int j = 0; j < 8; ++j) {
        float z = (v[j] - mean) * rstd;
        if (HAS_SB) z = z * sc[c + j] + bi[c + j];
        o8[j] = f2bf(z);
    }
    uint4 pk;
    pk.x = (uint32_t)o8[0] | ((uint32_t)o8[1] << 16);
    pk.y = (uint32_t)o8[2] | ((uint32_t)o8[3] << 16);
    pk.z = (uint32_t)o8[4] | ((uint32_t)o8[5] << 16);
    pk.w = (uint32_t)o8[6] | ((uint32_t)o8[7] << 16);
    *reinterpret_cast<uint4*>(out + row * 512 + c) = pk;
}

// ---------- weight transpose-convert: f32 [L][K][N] -> bf16 [L][row0+N][K], opt row-scale ----------
__global__ __launch_bounds__(256)
void wtrans(const float* __restrict__ W, uint16_t* __restrict__ WT, int K, int N,
            size_t lstride, int row0, const float* __restrict__ kscale)
{
    __shared__ float tile[32][33];
    const int l = blockIdx.z;
    const int k0 = blockIdx.x * 32, n0 = blockIdx.y * 32;
    const float* Wl = W + (size_t)l * K * N;
    uint16_t* WTl = WT + (size_t)l * lstride;
    const int tx = threadIdx.x, ty = threadIdx.y;  // (32,8)
#pragma unroll
    for (int j = 0; j < 4; ++j) {
        const int k = k0 + ty + j * 8;
        float w = Wl[(size_t)k * N + n0 + tx];
        if (kscale) w *= kscale[l * K + k];
        tile[ty + j * 8][tx] = w;
    }
    __syncthreads();
#pragma unroll
    for (int j = 0; j < 4; ++j)
        WTl[(size_t)(row0 + n0 + ty + j * 8) * K + k0 + tx] = f2bf(tile[tx][ty + j * 8]);
}

// ---------- bias fold: out[l*1024 + (z?512:0) + n] = sum_k b[l][k] * W[l][k][n] ----------
__global__ __launch_bounds__(256)
void bfold(const float* __restrict__ b, const float* __restrict__ Wq,
           const float* __restrict__ Wk, float* __restrict__ out)
{
    const int n = blockIdx.x * 256 + threadIdx.x;   // grid (2, 6, 2)
    const int l = blockIdx.y, sel = blockIdx.z;
    const float* bb = b + l * 512;
    const float* W = (sel ? Wk : Wq) + (size_t)l * 512 * 512;
    float s = 0.f;
    for (int k = 0; k < 512; ++k) s += bb[k] * W[(size_t)k * 512 + n];
    out[l * 1024 + sel * 512 + n] = s;
}

// ---------- GEMM v8: counted-vmcnt depth-2, 2D-rect XCD swizzle, coalesced epilogues ----------
// C[M,N] = A[M,K] @ BT[N,K]^T. Requires (M/BM)%2==0, (N/BN)%4==0.
// OUT_VT: 1 = all cols scatter to vt[bh][d][n]; 2 = cols >= 1024 scatter, rest normal.
template<int BM, int BN, int NWR, int NWC, int MINW,
         int HAS_BIAS, int HAS_RESID, int DO_GELU, int OUT_BF16, int OUT_VT>
__global__ __launch_bounds__(NWR * NWC * 64, MINW)
void gemm8(const uint16_t* __restrict__ A, const uint16_t* __restrict__ BT,
           const float* __restrict__ bias, const float* __restrict__ resid,
           void* __restrict__ outp, uint16_t* __restrict__ vt,
           int M, int N, int K)
{
    constexpr int NT = NWR * NWC * 64;
    constexpr int WM = BM / NWR, WN = BN / NWC;
    constexpr int FM = WM / 16, FN = WN / 16;
    constexpr int ASLOTS = 8 * BM, BSLOTS = 8 * BN, TOT = ASLOTS + BSLOTS;
    constexpr int S = TOT / NT;
    static_assert(S == 4, "vmcnt literal assumes S==4");
    static_assert(BM * BN <= 2 * ASLOTS * 8, "epilogue LDS reuse needs BN<=128");
    __shared__ uint16_t As[2][ASLOTS * 8];
    __shared__ uint16_t Bs[2][BSLOTS * 8];
    const int tid = threadIdx.x, lane = tid & 63;
    const int w = tid >> 6, wr = w / NWC, wc = w % NWC;
    const int kg = lane >> 4, lr = lane & 15;
    // 2D-rectangle XCD swizzle: each XCD owns an (nbm/2)x(nbn/4) tile rectangle.
    const int nbn = N / BN, nbm = M / BM;
    const int rect_m = nbm >> 1, rect_n = nbn >> 2;
    const int xcd = blockIdx.x & 7, c = blockIdx.x >> 3;
    const int bm = (xcd >> 2) * rect_m + c / rect_n;
    const int bn = (xcd & 3) * rect_n + c % rect_n;
    const size_t m0 = (size_t)bm * BM;
    const size_t n0 = (size_t)bn * BN;

    auto stage = [&](int b, int k0) {
#pragma unroll
        for (int j = 0; j < S; ++j) {
            const int s = j * NT + tid;
            if (s < ASLOTS) {
                const int sub = s / BM, row = s % BM;
                async_lds16(A + (m0 + row) * K + k0 + sub * 8, &As[b][s * 8]);
            } else {
                const int s2 = s - ASLOTS;
                const int sub = s2 / BN, row = s2 % BN;
                async_lds16(BT + (n0 + row) * K + k0 + sub * 8, &Bs[b][s2 * 8]);
            }
        }
    };

    f32x4 acc[FM][FN] = {};
    const int nt = K / 64;
    stage(0, 0);
    stage(1, 64);
    int cur = 0;
    for (int t = 0; t < nt; ++t) {
        if (t < nt - 1) wait_vmcnt<S>(); else wait_vmcnt<0>();
        SBAR;
        s16x8 af[2][FM], bf[2][FN];
#pragma unroll
        for (int ks = 0; ks < 2; ++ks) {
#pragma unroll
            for (int i = 0; i < FM; ++i)
                af[ks][i] = *(const s16x8*)&As[cur][((ks * 4 + kg) * BM + wr * WM + i * 16 + lr) * 8];
#pragma unroll
            for (int j = 0; j < FN; ++j)
                bf[ks][j] = *(const s16x8*)&Bs[cur][((ks * 4 + kg) * BN + wc * WN + j * 16 + lr) * 8];
        }
        __builtin_amdgcn_s_setprio(1);
#pragma unroll
        for (int ks = 0; ks < 2; ++ks)
#pragma unroll
            for (int i = 0; i < FM; ++i)
#pragma unroll
                for (int j = 0; j < FN; ++j)
                    acc[i][j] = mfma16(af[ks][i], bf[ks][j], acc[i][j]);
        __builtin_amdgcn_s_setprio(0);
        LGKM0; SCHED0;
        SBAR;
        if (t + 2 < nt) stage(cur, (t + 2) * 64);
        cur ^= 1;
    }
    // ---- epilogues (LDS reuse is safe: every wave did lgkmcnt(0) before final barrier) ----
    uint16_t* lt = (uint16_t*)As;   // BM*BN bf16 tile buffer
    if (OUT_VT == 1 || (OUT_VT == 2 && n0 >= 1024)) {
        // stage COL-major (transposed) with XOR swizzle, then coalesced writes to vt
#pragma unroll
        for (int i = 0; i < FM; ++i) {
            const int rl0 = wr * WM + i * 16 + kg * 4;
#pragma unroll
            for (int j = 0; j < FN; ++j) {
                const int cl = wc * WN + j * 16 + lr;
                const int gcol = (int)n0 + cl;
                const int c2 = (OUT_VT == 2) ? gcol - 1024 : gcol;
                const float bval = HAS_BIAS ? bias[c2] : 0.0f;
#pragma unroll
                for (int r = 0; r < 4; ++r) {
                    const int rl = rl0 + r;
                    lt[cl * BM + (rl ^ ((cl & 7) << 3))] = f2bf(acc[i][j][r] + bval);
                }
            }
        }
        __syncthreads();
        const int b = (int)(m0 >> 10), nloc = (int)(m0 & 1023);
        constexpr int PER = BM * BN / 8 / NT;
#pragma unroll
        for (int cth = 0; cth < PER; ++cth) {
            const int s = cth * NT + tid;
            const int cl = s / (BM / 8), rc = s % (BM / 8);
            uint4 val = *(const uint4*)&lt[cl * BM + (rc ^ (cl & 7)) * 8];
            const int gcol = (int)n0 + cl;
            const int c2 = (OUT_VT == 2) ? gcol - 1024 : gcol;
            const int h = c2 >> 6, d = c2 & 63;
            *(uint4*)&vt[((size_t)(b * 8 + h) * 64 + d) * 1024 + nloc + rc * 8] = val;
        }
        return;
    }
    if (OUT_BF16) {
        // stage ROW-major with XOR swizzle, then coalesced 16B writes
#pragma unroll
        for (int i = 0; i < FM; ++i) {
            const int rl0 = wr * WM + i * 16 + kg * 4;
#pragma unroll
            for (int j = 0; j < FN; ++j) {
                const int cl = wc * WN + j * 16 + lr;
                const float bval = HAS_BIAS ? bias[n0 + cl] : 0.0f;
#pragma unroll
                for (int r = 0; r < 4; ++r) {
                    const int rl = rl0 + r;
                    float v = acc[i][j][r] + bval;
                    if (DO_GELU) v = gelu_exact(v);
                    lt[rl * BN + (cl ^ ((rl & 7) << 3))] = f2bf(v);
                }
            }
        }
        __syncthreads();
        constexpr int PER = BM * BN / 8 / NT;
#pragma unroll
        for (int cth = 0; cth < PER; ++cth) {
            const int s = cth * NT + tid;
            const int rl = s / (BN / 8), cc = s % (BN / 8);
            uint4 val = *(const uint4*)&lt[rl * BN + (cc ^ (rl & 7)) * 8];
            *(uint4*)&((uint16_t*)outp)[(m0 + rl) * N + n0 + cc * 8] = val;
        }
        return;
    }
    // f32 + residual path (direct stores)
#pragma unroll
    for (int i = 0; i < FM; ++i) {
        const size_t rbase = m0 + wr * WM + i * 16 + kg * 4;
#pragma unroll
        for (int j = 0; j < FN; ++j) {
            const size_t col = n0 + wc * WN + j * 16 + lr;
            const float bval = HAS_BIAS ? bias[col] : 0.0f;
#pragma unroll
            for (int r = 0; r < 4; ++r) {
                const size_t row = rbase + r;
                float v = acc[i][j][r] + bval;
                if (DO_GELU)  v = gelu_exact(v);
                if (HAS_RESID) v += resid[row * (size_t)N + col];
                ((float*)outp)[row * (size_t)N + col] = v;
            }
        }
    }
}

// ---------- flash attention: no-max softmax, fragment-ordered LDS, 1 barrier/tile ----------
__global__ __launch_bounds__(256)
void attn_flash(const uint16_t* __restrict__ Qb, const uint16_t* __restrict__ Kb,
                const uint16_t* __restrict__ Vt, uint16_t* __restrict__ Ob,
                int qstride, int kstride, int qoff, int koff)
{
    __shared__ uint16_t Ks[2][4096];   // [sub=d/8 8][kv 64][8] fragment-ordered
    __shared__ uint16_t Vs[2][4096];   // [sub=kv/8 8][d 64][8] fragment-ordered
    __shared__ uint16_t Pb[4][1024];   // per-wave [sub=kv/8 8][qrow 16][8]
    const int tid = threadIdx.x, lane = tid & 63, w = tid >> 6;
    const int kg = lane >> 4, lr = lane & 15;
    const int bh = blockIdx.y, b = bh >> 3, h = bh & 7;
    const int q0 = blockIdx.x * 64;
    const float CEXP = 0.125f * 1.44269504f;

    s16x8 aq0, aq1;
    {
        const size_t qrow = (size_t)b * 1024 + q0 + w * 16 + lr;
        const uint16_t* qp = Qb + qrow * qstride + qoff + h * 64 + kg * 8;
        aq0 = *(const s16x8*)qp;
        aq1 = *(const s16x8*)(qp + 32);
    }
    const uint16_t* kbase = Kb + (size_t)b * 1024 * kstride + koff + h * 64;
    const uint16_t* vbase = Vt + (size_t)bh * 65536;

    float l_r[4] = {0.f, 0.f, 0.f, 0.f};
    f32x4 acc[4] = {};

    auto stage = [&](int buf, int kv0) {
#pragma unroll
        for (int j = 0; j < 2; ++j) {
            const int s = j * 256 + tid;
            const int sub = s >> 6, row = s & 63;
            async_lds16(kbase + (size_t)(kv0 + row) * kstride + sub * 8, &Ks[buf][s * 8]);
            async_lds16(vbase + (size_t)row * 1024 + kv0 + sub * 8,      &Vs[buf][s * 8]);
        }
    };

    stage(0, 0);
    __syncthreads();
    int cur = 0;
    for (int t = 0; t < 16; ++t) {
        if (t < 15) stage(cur ^ 1, (t + 1) * 64);
        f32x4 s4[4];
        __builtin_amdgcn_s_setprio(1);
#pragma unroll
        for (int ni = 0; ni < 4; ++ni) {
            s16x8 bk0 = *(const s16x8*)&Ks[cur][(kg * 64 + ni * 16 + lr) * 8];
            s16x8 bk1 = *(const s16x8*)&Ks[cur][((4 + kg) * 64 + ni * 16 + lr) * 8];
            f32x4 z = {};
            z = mfma16(aq0, bk0, z);
            z = mfma16(aq1, bk1, z);
            s4[ni] = z;
        }
        __builtin_amdgcn_s_setprio(0);
#pragma unroll
        for (int ni = 0; ni < 4; ++ni) {
            const int slotb = (ni * 2 + (lr >> 3)) * 16 + kg * 4;
#pragma unroll
            for (int r = 0; r < 4; ++r) {
                const float pe = __builtin_amdgcn_exp2f(s4[ni][r] * CEXP);
                l_r[r] += pe;
                Pb[w][(slotb + r) * 8 + (lr & 7)] = f2bf(pe);
            }
        }
        s16x8 ap0 = *(const s16x8*)&Pb[w][(kg * 16 + lr) * 8];
        s16x8 ap1 = *(const s16x8*)&Pb[w][((4 + kg) * 16 + lr) * 8];
        __builtin_amdgcn_s_setprio(1);
#pragma unroll
        for (int ni = 0; ni < 4; ++ni) {
            s16x8 bv0 = *(const s16x8*)&Vs[cur][(kg * 64 + ni * 16 + lr) * 8];
            s16x8 bv1 = *(const s16x8*)&Vs[cur][((4 + kg) * 64 + ni * 16 + lr) * 8];
            acc[ni] = mfma16(ap0, bv0, acc[ni]);
            acc[ni] = mfma16(ap1, bv1, acc[ni]);
        }
        __builtin_amdgcn_s_setprio(0);
        __syncthreads();
        cur ^= 1;
    }
    float linv[4];
#pragma unroll
    for (int r = 0; r < 4; ++r) {
        float l = l_r[r];
        l += __shfl_xor(l, 1); l += __shfl_xor(l, 2);
        l += __shfl_xor(l, 4); l += __shfl_xor(l, 8);
        linv[r] = 1.0f / l;
    }
#pragma unroll
    for (int ni = 0; ni < 4; ++ni)
#pragma unroll
        for (int r = 0; r < 4; ++r) {
            const float v = acc[ni][r] * linv[r];
            const size_t row = (size_t)b * 1024 + q0 + w * 16 + kg * 4 + r;
            Ob[row * 512 + h * 64 + ni * 16 + lr] = f2bf(v);
        }
}

// ---------- host ----------
extern "C" void kernel_launch(void* const* d_in, const int* in_sizes, int n_in,
                              void* d_out, int out_size, void* d_ws, size_t ws_size,
                              hipStream_t stream)
{
    (void)in_sizes; (void)n_in; (void)out_size; (void)ws_size;
    const float* g     = (const float*)d_in[0];
    const float* x0    = (const float*)d_in[1];
    const float* ln1_s = (const float*)d_in[2];
    const float* ln1_b = (const float*)d_in[3];
    const float* Wqkv  = (const float*)d_in[4];
    const float* Wo_sa = (const float*)d_in[5];
    const float* bo_sa = (const float*)d_in[6];
    const float* lng_s = (const float*)d_in[7];
    const float* lng_b = (const float*)d_in[8];
    const float* lnx_s = (const float*)d_in[9];
    const float* lnx_b = (const float*)d_in[10];
    const float* Wq    = (const float*)d_in[11];
    const float* Wk    = (const float*)d_in[12];
    const float* Wv    = (const float*)d_in[13];
    const float* bv    = (const float*)d_in[14];
    const float* Wo_ca = (const float*)d_in[15];
    const float* bo_ca = (const float*)d_in[16];
    const float* lnf_s = (const float*)d_in[17];
    const float* lnf_b = (const float*)d_in[18];
    const float* W1    = (const float*)d_in[19];
    const float* b1    = (const float*)d_in[20];
    const float* W2    = (const float*)d_in[21];
    const float* b2    = (const float*)d_in[22];

    float* x = (float*)d_out;  // running residual stream (f32)

    char* p = (char*)d_ws;
    auto carve = [&](size_t n) { char* r = p; p += (n + 255) & ~(size_t)255; return r; };
    uint16_t* WqkT  = (uint16_t*)carve(6ull * 1024 * 512 * 2);  // scaled [l][WqT|WkT][512]
    uint16_t* WvT   = (uint16_t*)carve(6ull * 512 * 512 * 2);
    uint16_t* WocaT = (uint16_t*)carve(6ull * 512 * 512 * 2);
    uint16_t* WqkvT = (uint16_t*)carve(6ull * 1536 * 512 * 2);
    uint16_t* WosaT = (uint16_t*)carve(6ull * 512 * 512 * 2);
    uint16_t* W1T   = (uint16_t*)carve(6ull * 2048 * 512 * 2);
    uint16_t* W2T   = (uint16_t*)carve(6ull * 512 * 2048 * 2);
    float*    bqk   = (float*)carve(6144ull * 4);               // folded LN-bias @ W
    uint16_t* zg    = (uint16_t*)carve(4096ull * 512 * 2);      // standardized g
    uint16_t* qkall = (uint16_t*)carve(4096ull * 6144 * 2);     // all layers' Q|K
    uint16_t* xn    = (uint16_t*)carve(4096ull * 512 * 2);
    uint16_t* qkvu  = (uint16_t*)carve(4096ull * 1536 * 2);
    uint16_t* vt    = (uint16_t*)carve(32ull * 64 * 1024 * 2);
    uint16_t* ab    = (uint16_t*)carve(4096ull * 512 * 2);
    uint16_t* hb    = (uint16_t*)carve(4096ull * 2048 * 2);

    // ---- prep: weights (QK scale-folded), bias fold ----
    dim3 tb(32, 8);
    wtrans<<<dim3(16, 16, 6), tb, 0, stream>>>(Wq,    WqkT,  512, 512,  1024ull * 512, 0,   lng_s);
    wtrans<<<dim3(16, 16, 6), tb, 0, stream>>>(Wk,    WqkT,  512, 512,  1024ull * 512, 512, lng_s);
    wtrans<<<dim3(16, 16, 6), tb, 0, stream>>>(Wv,    WvT,   512, 512,  512ull * 512, 0, nullptr);
    wtrans<<<dim3(16, 16, 6), tb, 0, stream>>>(Wo_ca, WocaT, 512, 512,  512ull * 512, 0, nullptr);
    wtrans<<<dim3(16, 48, 6), tb, 0, stream>>>(Wqkv,  WqkvT, 512, 1536, 1536ull * 512, 0, nullptr);
    wtrans<<<dim3(16, 16, 6), tb, 0, stream>>>(Wo_sa, WosaT, 512, 512,  512ull * 512, 0, nullptr);
    wtrans<<<dim3(16, 64, 6), tb, 0, stream>>>(W1,    W1T,   512, 2048, 2048ull * 512, 0, nullptr);
    wtrans<<<dim3(64, 16, 6), tb, 0, stream>>>(W2,    W2T,   2048, 512, 2048ull * 512, 0, nullptr);
    bfold<<<dim3(2, 6, 2), 256, 0, stream>>>(lng_b, Wq, Wk, bqk);

    hipMemcpyAsync(x, x0, 4096ull * 512 * 4, hipMemcpyDeviceToDevice, stream);

    // ---- hoisted Q/K for all layers: qkall = z(g) @ WqkT + bqk ----
    ln_t<0><<<1024, 256, 0, stream>>>(g, nullptr, nullptr, zg);
    ln_t<1><<<1024, 256, 0, stream>>>(x, lnx_s, lnx_b, xn);   // lnx layer 0
    gemm8<128, 128, 2, 4, 4, 1, 0, 0, 1, 0><<<1536, 512, 0, stream>>>(
        zg, WqkT, bqk, nullptr, qkall, nullptr, 4096, 6144, 512);

    const dim3 ga(16, 32);

    for (int l = 0; l < 6; ++l) {
        const size_t o512 = (size_t)l * 512, oW = (size_t)l * 512 * 512;
        const size_t oW1 = (size_t)l * 2048 * 512, oWqkv = (size_t)l * 1536 * 512;
        const size_t o2048 = (size_t)l * 2048;

        // ---- relational cross attention (Q,K precomputed) ----
        gemm8<64, 64, 2, 2, 4, 1, 0, 0, 0, 1><<<512, 256, 0, stream>>>(
            xn, WvT + oW, bv + o512, nullptr, nullptr, vt, 4096, 512, 512);
        attn_flash<<<ga, 256, 0, stream>>>(qkall, qkall, vt, ab, 6144, 6144,
                                           l * 1024, l * 1024 + 512);
        gemm8<64, 64, 2, 2, 4, 1, 1, 0, 0, 0><<<512, 256, 0, stream>>>(
            ab, WocaT + oW, bo_ca + o512, x, x, nullptr, 4096, 512, 512);

        // ---- feed-forward 1 ----
        ln_t<1><<<1024, 256, 0, stream>>>(x, lnf_s + o512, lnf_b + o512, xn);
        gemm8<128, 128, 2, 4, 4, 1, 0, 1, 1, 0><<<512, 512, 0, stream>>>(
            xn, W1T + oW1, b1 + o2048, nullptr, hb, nullptr, 4096, 2048, 512);
        gemm8<64, 64, 2, 2, 4, 1, 1, 0, 0, 0><<<512, 256, 0, stream>>>(
            hb, W2T + oW1, b2 + o512, x, x, nullptr, 4096, 512, 2048);
        ln_t<1><<<1024, 256, 0, stream>>>(x, ln1_s + o512, ln1_b + o512, xn);

        // ---- pre-norm self attention ----
        gemm8<128, 128, 2, 4, 4, 0, 0, 0, 1, 2><<<384, 512, 0, stream>>>(
            xn, WqkvT + oWqkv, nullptr, nullptr, qkvu, vt, 4096, 1536, 512);
        attn_flash<<<ga, 256, 0, stream>>>(qkvu, qkvu, vt, ab, 1536, 1536, 0, 512);
        gemm8<64, 64, 2, 2, 4, 1, 1, 0, 0, 0><<<512, 256, 0, stream>>>(
            ab, WosaT + oW, bo_sa + o512, x, x, nullptr, 4096, 512, 512);

        // ---- feed-forward 2 ----
        ln_t<1><<<1024, 256, 0, stream>>>(x, lnf_s + o512, lnf_b + o512, xn);
        gemm8<128, 128, 2, 4, 4, 1, 0, 1, 1, 0><<<512, 512, 0, stream>>>(
            xn, W1T + oW1, b1 + o2048, nullptr, hb, nullptr, 4096, 2048, 512);
        gemm8<64, 64, 2, 2, 4, 1, 1, 0, 0, 0><<<512, 256, 0, stream>>>(
            hb, W2T + oW1, b2 + o512, x, x, nullptr, 4096, 512, 2048);
        if (l < 5)
            ln_t<1><<<1024, 256, 0, stream>>>(x, lnx_s + o512 + 512, lnx_b + o512 + 512, xn);
    }
}